// Round 5
// baseline (701.180 us; speedup 1.0000x reference)
//
#include <hip/hip_runtime.h>
#include <hip/hip_bf16.h>
#include <math.h>

#define N_NODES 10000
#define N_EDGES 100000
#define F_IN    128
#define CH      120
#define NH      16
#define NEG_SLOPE 0.2f
#define MPAD    10112          // N padded to multiple of 128

typedef unsigned short ushort_t;
typedef short short8 __attribute__((ext_vector_type(8)));
typedef float floatx4 __attribute__((ext_vector_type(4)));

__device__ inline ushort_t f2b(float f) {            // fp32->bf16 RNE
    unsigned u = __float_as_uint(f);
    unsigned r = (u + 0x7fffu + ((u >> 16) & 1u)) >> 16;
    return (ushort_t)r;
}
__device__ inline float b2f(ushort_t u) { return __uint_as_float(((unsigned)u) << 16); }

// async global->LDS, 16B per lane (dest = wave-uniform base + lane*16)
__device__ __forceinline__ void gload16(const ushort_t* g, ushort_t* l) {
    __builtin_amdgcn_global_load_lds(
        (const __attribute__((address_space(1))) unsigned int*)g,
        (__attribute__((address_space(3))) unsigned int*)l,
        16, 0, 0);
}

// ======================== bf16 MFMA GEMM (m97 structure) ========================
// C[M,Nn] = A[M,K] @ Bt[Nn,K]^T. A stride K, Bt stride K; K multiple of 32.
#define GBM 128
#define GBN 128
#define GBK 32

template<int ACT, int OUTBF>   // ACT: 0 none 1 relu; OUTBF: bf16 out?
__global__ __launch_bounds__(256) void gemm_mfma_kernel(
    const ushort_t* __restrict__ A, const ushort_t* __restrict__ Bt,
    const float* __restrict__ bias, void* __restrict__ Cv,
    int M, int Nn, int K)
{
    __shared__ ushort_t As[GBM * GBK];
    __shared__ ushort_t Bs[GBN * GBK];
    const int t = threadIdx.x;
    const int lane = t & 63;
    const int wid = t >> 6;
    const int wr = wid >> 1, wc = wid & 1;
    const int row0 = blockIdx.y * GBM, col0 = blockIdx.x * GBN;
    const int laneRow = lane & 15;
    const int laneK   = (lane >> 4) * 8;
    const int srow = lane >> 2;
    const int skq  = (lane & 3) * 8;

    floatx4 acc[4][4];
#pragma unroll
    for (int m = 0; m < 4; ++m)
#pragma unroll
        for (int n = 0; n < 4; ++n)
            acc[m][n] = (floatx4){0.f, 0.f, 0.f, 0.f};

    for (int k0 = 0; k0 < K; k0 += GBK) {
#pragma unroll
        for (int i = 0; i < 2; ++i) {
            int ai = wid * 2 + i;
            gload16(A + (size_t)(row0 + ai * 16 + srow) * K + k0 + skq,
                    &As[ai * 512]);
        }
#pragma unroll
        for (int i = 0; i < 2; ++i) {
            int bi = wid * 2 + i;
            gload16(Bt + (size_t)(col0 + bi * 16 + srow) * K + k0 + skq,
                    &Bs[bi * 512]);
        }
        __syncthreads();

        short8 af[4], bf[4];
#pragma unroll
        for (int m = 0; m < 4; ++m)
            af[m] = *reinterpret_cast<const short8*>(
                &As[(wr * 64 + m * 16 + laneRow) * GBK + laneK]);
#pragma unroll
        for (int n = 0; n < 4; ++n)
            bf[n] = *reinterpret_cast<const short8*>(
                &Bs[(wc * 64 + n * 16 + laneRow) * GBK + laneK]);
#pragma unroll
        for (int m = 0; m < 4; ++m)
#pragma unroll
            for (int n = 0; n < 4; ++n)
                acc[m][n] = __builtin_amdgcn_mfma_f32_16x16x32_bf16(
                    af[m], bf[n], acc[m][n], 0, 0, 0);
        __syncthreads();
    }

    const int orow = (lane >> 4) * 4;   // C/D: col=lane&15, row=(lane>>4)*4+j
#pragma unroll
    for (int m = 0; m < 4; ++m) {
#pragma unroll
        for (int n = 0; n < 4; ++n) {
            int gc = col0 + wc * 64 + n * 16 + laneRow;
            if (gc >= Nn) continue;
            float bv = bias ? bias[gc] : 0.f;
#pragma unroll
            for (int j = 0; j < 4; ++j) {
                int gr = row0 + wr * 64 + m * 16 + orow + j;
                if (gr >= M) continue;
                float v = acc[m][n][j] + bv;
                if (ACT == 1) v = fmaxf(v, 0.f);
                if (OUTBF) ((ushort_t*)Cv)[(size_t)gr * Nn + gc] = f2b(v);
                else       ((float*)Cv)   [(size_t)gr * Nn + gc] = v;
            }
        }
    }
}

// ---- split-K variant: fp32 atomicAdd into C (C pre-zeroed), no bias/act
__global__ __launch_bounds__(256) void gemm_splitk_kernel(
    const ushort_t* __restrict__ A, const ushort_t* __restrict__ Bt,
    float* __restrict__ C, int M, int Nn, int K, int KS)
{
    __shared__ ushort_t As[GBM * GBK];
    __shared__ ushort_t Bs[GBN * GBK];
    const int t = threadIdx.x;
    const int lane = t & 63;
    const int wid = t >> 6;
    const int wr = wid >> 1, wc = wid & 1;
    const int row0 = blockIdx.y * GBM, col0 = blockIdx.x * GBN;
    const int kbeg = blockIdx.z * KS, kend = kbeg + KS;
    const int laneRow = lane & 15;
    const int laneK   = (lane >> 4) * 8;
    const int srow = lane >> 2;
    const int skq  = (lane & 3) * 8;

    floatx4 acc[4][4];
#pragma unroll
    for (int m = 0; m < 4; ++m)
#pragma unroll
        for (int n = 0; n < 4; ++n)
            acc[m][n] = (floatx4){0.f, 0.f, 0.f, 0.f};

    for (int k0 = kbeg; k0 < kend; k0 += GBK) {
#pragma unroll
        for (int i = 0; i < 2; ++i) {
            int ai = wid * 2 + i;
            gload16(A + (size_t)(row0 + ai * 16 + srow) * K + k0 + skq,
                    &As[ai * 512]);
        }
#pragma unroll
        for (int i = 0; i < 2; ++i) {
            int bi = wid * 2 + i;
            gload16(Bt + (size_t)(col0 + bi * 16 + srow) * K + k0 + skq,
                    &Bs[bi * 512]);
        }
        __syncthreads();

        short8 af[4], bf[4];
#pragma unroll
        for (int m = 0; m < 4; ++m)
            af[m] = *reinterpret_cast<const short8*>(
                &As[(wr * 64 + m * 16 + laneRow) * GBK + laneK]);
#pragma unroll
        for (int n = 0; n < 4; ++n)
            bf[n] = *reinterpret_cast<const short8*>(
                &Bs[(wc * 64 + n * 16 + laneRow) * GBK + laneK]);
#pragma unroll
        for (int m = 0; m < 4; ++m)
#pragma unroll
            for (int n = 0; n < 4; ++n)
                acc[m][n] = __builtin_amdgcn_mfma_f32_16x16x32_bf16(
                    af[m], bf[n], acc[m][n], 0, 0, 0);
        __syncthreads();
    }

    const int orow = (lane >> 4) * 4;
#pragma unroll
    for (int m = 0; m < 4; ++m) {
#pragma unroll
        for (int n = 0; n < 4; ++n) {
            int gc = col0 + wc * 64 + n * 16 + laneRow;
            if (gc >= Nn) continue;
#pragma unroll
            for (int j = 0; j < 4; ++j) {
                int gr = row0 + wr * 64 + m * 16 + orow + j;
                if (gr >= M) continue;
                atomicAdd(&C[(size_t)gr * Nn + gc], acc[m][n][j]);
            }
        }
    }
}

// ======================== transpose + f32->bf16 ========================
__global__ __launch_bounds__(256) void transpose_b_kernel(
    const float* __restrict__ in, ushort_t* __restrict__ out,
    int R, int Cc, int Kpad)
{
    __shared__ float tile[32][33];
    const int tx = threadIdx.x & 31, ty = threadIdx.x >> 5;
    const int k0 = blockIdx.x * 32, n0 = blockIdx.y * 32;
#pragma unroll
    for (int i = 0; i < 4; ++i) {
        int r = k0 + ty + i * 8, c = n0 + tx;
        tile[ty + i * 8][tx] = (r < R && c < Cc) ? in[(size_t)r * Cc + c] : 0.f;
    }
    __syncthreads();
#pragma unroll
    for (int i = 0; i < 4; ++i) {
        int orow = n0 + ty + i * 8, ocol = k0 + tx;
        out[(size_t)orow * Kpad + ocol] = f2b(tile[tx][ty + i * 8]);
    }
}

// ======================== conversions ========================
__global__ void f2b_kernel(const float* __restrict__ in, ushort_t* __restrict__ out, int n)
{
    int i4 = (blockIdx.x * blockDim.x + threadIdx.x) * 4;
    if (i4 + 4 <= n) {
        float4 v = *reinterpret_cast<const float4*>(in + i4);
        ushort4 o = make_ushort4(f2b(v.x), f2b(v.y), f2b(v.z), f2b(v.w));
        *reinterpret_cast<ushort4*>(out + i4) = o;
    } else {
        for (; i4 < n; ++i4) out[i4] = f2b(in[i4]);
    }
}

// ======================== edge-index dtype handling ========================
__global__ void detect_kernel(const int* __restrict__ w, int nwords, int* flag)
{
    int i = blockIdx.x * blockDim.x + threadIdx.x;
    int odd = 2 * i + 1;
    if (odd < nwords && w[odd] != 0) atomicOr(flag, 1);
}

// decode edges + dst histogram in one pass
__global__ void convert_hist_kernel(const int* __restrict__ w, const int* __restrict__ flag,
                                    int* __restrict__ src, int* __restrict__ dst,
                                    int* __restrict__ deg, int E)
{
    int i = blockIdx.x * blockDim.x + threadIdx.x;
    if (i >= E) return;
    int s, d;
    if (*flag == 0) { s = w[2 * i]; d = w[2 * E + 2 * i]; }
    else            { s = w[i];     d = w[E + i]; }
    src[i] = s; dst[i] = d;
    atomicAdd(deg + d, 1);
}

// ======================== CSR build ========================
#define SCAN_T 1024
__global__ __launch_bounds__(SCAN_T) void scan_kernel(
    const int* __restrict__ deg, int* __restrict__ off, int n)
{
    __shared__ int part[SCAN_T];
    int t = threadIdx.x;
    int per = (n + SCAN_T - 1) / SCAN_T;
    int b0 = t * per, b1 = min(b0 + per, n);
    int s = 0;
    for (int i = b0; i < b1; ++i) s += deg[i];
    part[t] = s;
    __syncthreads();
    for (int d = 1; d < SCAN_T; d <<= 1) {
        int v = (t >= d) ? part[t - d] : 0;
        __syncthreads();
        part[t] += v;
        __syncthreads();
    }
    int run = (t == 0) ? 0 : part[t - 1];
    for (int i = b0; i < b1; ++i) { off[i] = run; run += deg[i]; }
    if (t == SCAN_T - 1) off[n] = run;
}

__global__ void scatter_kernel(const int* __restrict__ src, const int* __restrict__ dst,
                               const int* __restrict__ off, int* __restrict__ cnt,
                               int* __restrict__ srcs, int E)
{
    int i = blockIdx.x * blockDim.x + threadIdx.x;
    if (i >= E) return;
    int d = dst[i];
    int pos = off[d] + atomicAdd(cnt + d, 1);
    srcs[pos] = src[i];
}

// ======================== attention logits ========================
__global__ void al_bf16_kernel(const ushort_t* __restrict__ h,
                               const float* __restrict__ a_s, const float* __restrict__ a_d,
                               float* __restrict__ als, float* __restrict__ ald,
                               int Nn, int Hh, int Cc)
{
    int wid  = (blockIdx.x * blockDim.x + threadIdx.x) >> 6;
    int lane = threadIdx.x & 63;
    if (wid >= Nn * Hh) return;
    int n = wid / Hh, hh = wid - n * Hh;
    const ushort_t* hp = h + (size_t)n * Hh * Cc + hh * Cc;
    float s1 = 0.f, s2 = 0.f;
    int c = lane * 2;
    if (c < Cc) {
        unsigned w = *reinterpret_cast<const unsigned*>(hp + c);
        float f0 = b2f((ushort_t)(w & 0xffffu)), f1 = b2f((ushort_t)(w >> 16));
        float2 as2 = *reinterpret_cast<const float2*>(a_s + hh * Cc + c);
        float2 ad2 = *reinterpret_cast<const float2*>(a_d + hh * Cc + c);
        s1 = f0 * as2.x + f1 * as2.y;
        s2 = f0 * ad2.x + f1 * ad2.y;
    }
#pragma unroll
    for (int o = 32; o; o >>= 1) {
        s1 += __shfl_down(s1, o);
        s2 += __shfl_down(s2, o);
    }
    if (lane == 0) { als[wid] = s1; ald[wid] = s2; }
}

// ======================== fused CSR segment softmax ========================
template<int HH, int LOGH>
__global__ void softmax_csr_kernel(const float* __restrict__ als,
                                   const float* __restrict__ ald,
                                   const int* __restrict__ off,
                                   const int* __restrict__ srcs,
                                   float* __restrict__ ebuf, int Nn)
{
    const int d = blockIdx.x * (blockDim.x >> 6) + (threadIdx.x >> 6);
    if (d >= Nn) return;
    const int lane = threadIdx.x & 63;
    const int h = lane & (HH - 1);
    const int j = lane >> LOGH;
    const int JS = 64 >> LOGH;
    const int start = off[d], end = off[d + 1];
    const float aldv = ald[d * HH + h];
    float m = -1e30f, ssum = 0.f;
    for (int base = start; base < end; base += JS) {
        int e = base + j;
        float v = -1e30f;
        if (e < end) {
            int s = srcs[e];
            float x = als[s * HH + h] + aldv;
            v = (x > 0.f) ? x : NEG_SLOPE * x;
            ebuf[(size_t)e * HH + h] = v;
        }
        float cm = v;
#pragma unroll
        for (int o = HH; o <= 32; o <<= 1) cm = fmaxf(cm, __shfl_xor(cm, o));
        float mnew = fmaxf(m, cm);
        float ex = (e < end) ? __expf(v - mnew) : 0.f;
#pragma unroll
        for (int o = HH; o <= 32; o <<= 1) ex += __shfl_xor(ex, o);
        ssum = ssum * __expf(m - mnew) + ex;
        m = mnew;
    }
    float rs = 1.f / ssum;
    for (int base = start; base < end; base += JS) {
        int e = base + j;
        if (e < end) {
            float v = ebuf[(size_t)e * HH + h];
            ebuf[(size_t)e * HH + h] = __expf(v - m) * rs;
        }
    }
}

// ======================== aggregation: one wave per dst node ========================
// out[d] = act( sum_e alpha_e * h[src_e] + bias ), bf16. No LDS, no syncs.
template<int HH, int ACT, int NCHUNK>
__global__ __launch_bounds__(256) void agg_wave_kernel(
    const ushort_t* __restrict__ h, const float* __restrict__ ebuf,
    const int* __restrict__ off, const int* __restrict__ srcs,
    const float* __restrict__ bias, ushort_t* __restrict__ outb,
    int F, int ostride, int Nn)
{
    const int d = blockIdx.x * 4 + (threadIdx.x >> 6);
    if (d >= Nn) return;
    const int lane = threadIdx.x & 63;
    const int start = off[d], end = off[d + 1];

    int cols[NCHUNK], hd[NCHUNK];
    float acc[NCHUNK][8];
#pragma unroll
    for (int c = 0; c < NCHUNK; ++c) {
        cols[c] = c * 512 + lane * 8;
        hd[c] = cols[c] / CH;           // 8-elem chunk stays in one head (120%8==0)
#pragma unroll
        for (int k = 0; k < 8; ++k) acc[c][k] = 0.f;
    }
    for (int e = start; e < end; ++e) {
        int s = srcs[e];
        const ushort_t* hp = h + (size_t)s * F;
#pragma unroll
        for (int c = 0; c < NCHUNK; ++c) {
            if (cols[c] < F) {
                float a = ebuf[(size_t)e * HH + hd[c]];
                short8 v = *reinterpret_cast<const short8*>(hp + cols[c]);
#pragma unroll
                for (int k = 0; k < 8; ++k)
                    acc[c][k] = fmaf(b2f((ushort_t)v[k]), a, acc[c][k]);
            }
        }
    }
#pragma unroll
    for (int c = 0; c < NCHUNK; ++c) {
        if (cols[c] < F) {
            short8 o;
#pragma unroll
            for (int k = 0; k < 8; ++k) {
                float v = acc[c][k] + bias[cols[c] + k];
                if (ACT) v = (v > 0.f) ? v : expm1f(v);
                o[k] = (short)f2b(v);
            }
            *reinterpret_cast<short8*>(outb + (size_t)d * ostride + cols[c]) = o;
        }
    }
}

// ======================== launch ========================
extern "C" void kernel_launch(void* const* d_in, const int* in_sizes, int n_in,
                              void* d_out, int out_size, void* d_ws, size_t ws_size,
                              hipStream_t stream)
{
    const float* x   = (const float*)d_in[0];
    const int*   ei  = (const int*)  d_in[1];
    const float* W1  = (const float*)d_in[2];
    const float* a1s = (const float*)d_in[3];
    const float* a1d = (const float*)d_in[4];
    const float* b1  = (const float*)d_in[5];
    const float* W2  = (const float*)d_in[6];
    const float* a2s = (const float*)d_in[7];
    const float* a2d = (const float*)d_in[8];
    const float* b2  = (const float*)d_in[9];
    const float* W3  = (const float*)d_in[10];
    const float* a3s = (const float*)d_in[11];
    const float* a3d = (const float*)d_in[12];
    const float* b3  = (const float*)d_in[13];
    const float* fcW = (const float*)d_in[14];
    const float* fcb = (const float*)d_in[15];

    float* out = (float*)d_out;
    const int N = N_NODES, E = N_EDGES;
    const int F16 = NH * CH;                 // 1920

    // ---- scratch inside d_out (FC overwrites all of d_out last)
    ushort_t* hraw  = (ushort_t*)out;                    // [MPAD][1920]
    ushort_t* hagg  = hraw + (size_t)MPAD * F16;         // [MPAD][1920]
    ushort_t* xb    = hagg + (size_t)MPAD * F16;         // [MPAD][128]
    ushort_t* W1t   = xb   + (size_t)MPAD * F_IN;        // [1920][128]
    ushort_t* W2t   = W1t  + (size_t)F16 * F_IN;         // [1920][1920]
    ushort_t* W3t   = W2t  + (size_t)F16 * F16;          // [128][1920]
    ushort_t* h3raw = W3t  + (size_t)128 * F16;          // [N][120] bf16
    float*    h3tmp = (float*)(h3raw + (size_t)N * CH);  // [N][120] fp32 (split-K)
    float*    als   = h3tmp + (size_t)N * CH;
    float*    ald   = als + (size_t)N * NH;
    float*    ebuf  = ald + (size_t)N * NH;              // [E][16] sorted alpha
    int*      srcv  = (int*)(ebuf + (size_t)E * NH);
    int*      dstv  = srcv + E;
    int*      srcs  = dstv + E;
    int*      flag  = srcs + E;
    int*      deg   = flag + 1;                          // [N]
    int*      offv  = deg + N;                           // [N+1]
    int*      cnt   = offv + N + 1;                      // [N]
    // ---- d_ws: FC inputs (read while FC writes d_out)
    ushort_t* h3bb = (ushort_t*)d_ws;                    // [MPAD][128]
    ushort_t* fcWt = h3bb + (size_t)MPAD * 128;          // [MPAD][128]

    // ---- edge decode + CSR build
    hipMemsetAsync(flag, 0, sizeof(int), stream);
    hipMemsetAsync(deg, 0, (size_t)N * 4, stream);
    hipMemsetAsync(cnt, 0, (size_t)N * 4, stream);
    detect_kernel      <<<(E + 255) / 256, 256, 0, stream>>>(ei, 2 * E, flag);
    convert_hist_kernel<<<(E + 255) / 256, 256, 0, stream>>>(ei, flag, srcv, dstv, deg, E);
    scan_kernel        <<<1, SCAN_T, 0, stream>>>(deg, offv, N);
    scatter_kernel     <<<(E + 255) / 256, 256, 0, stream>>>(srcv, dstv, offv, cnt, srcs, E);

    // ---- input/weight prep
    f2b_kernel<<<(N * F_IN / 4 + 255) / 256, 256, 0, stream>>>(x, xb, N * F_IN);
    dim3 tb(256);
    transpose_b_kernel<<<dim3(F_IN / 32, F16 / 32), tb, 0, stream>>>(W1, W1t, F_IN, F16, F_IN);
    transpose_b_kernel<<<dim3(F16 / 32, F16 / 32), tb, 0, stream>>>(W2, W2t, F16, F16, F16);
    transpose_b_kernel<<<dim3(F16 / 32, 128 / 32), tb, 0, stream>>>(W3, W3t, F16, CH, F16);
    transpose_b_kernel<<<dim3(128 / 32, MPAD / 32), tb, 0, stream>>>(fcW, fcWt, CH, N, 128);
    hipMemsetAsync(h3bb, 0, (size_t)MPAD * 128 * 2, stream);

    dim3 gBig(F16 / GBN, MPAD / GBM);        // (15,79)

    // =============== layer 1 ===============
    gemm_mfma_kernel<0, 1><<<gBig, 256, 0, stream>>>(xb, W1t, nullptr, hraw, N, F16, F_IN);
    al_bf16_kernel<<<(N * NH + 3) / 4, 256, 0, stream>>>(hraw, a1s, a1d, als, ald, N, NH, CH);
    softmax_csr_kernel<16, 4><<<(N + 3) / 4, 256, 0, stream>>>(als, ald, offv, srcs, ebuf, N);
    agg_wave_kernel<16, 1, 4><<<(N + 3) / 4, 256, 0, stream>>>(hraw, ebuf, offv, srcs, b1, hagg, F16, F16, N);

    // =============== layer 2 ===============
    gemm_mfma_kernel<0, 1><<<gBig, 256, 0, stream>>>(hagg, W2t, nullptr, hraw, N, F16, F16);
    al_bf16_kernel<<<(N * NH + 3) / 4, 256, 0, stream>>>(hraw, a2s, a2d, als, ald, N, NH, CH);
    softmax_csr_kernel<16, 4><<<(N + 3) / 4, 256, 0, stream>>>(als, ald, offv, srcs, ebuf, N);
    agg_wave_kernel<16, 1, 4><<<(N + 3) / 4, 256, 0, stream>>>(hraw, ebuf, offv, srcs, b2, hagg, F16, F16, N);

    // =============== layer 3 (H=1), split-K GEMM ===============
    hipMemsetAsync(h3tmp, 0, (size_t)N * CH * 4, stream);
    dim3 gL3(1, MPAD / GBM, 6);              // K split 1920 -> 6 x 320
    gemm_splitk_kernel<<<gL3, 256, 0, stream>>>(hagg, W3t, h3tmp, N, CH, F16, 320);
    f2b_kernel<<<(N * CH / 4 + 255) / 256, 256, 0, stream>>>(h3tmp, h3raw, N * CH);
    al_bf16_kernel<<<(N + 3) / 4, 256, 0, stream>>>(h3raw, a3s, a3d, als, ald, N, 1, CH);
    softmax_csr_kernel<1, 0><<<(N + 3) / 4, 256, 0, stream>>>(als, ald, offv, srcs, ebuf, N);
    agg_wave_kernel<1, 0, 1><<<(N + 3) / 4, 256, 0, stream>>>(h3raw, ebuf, offv, srcs, b3, h3bb, CH, 128, N);

    // =============== FC + ReLU ===============
    dim3 gFC(MPAD / GBN, MPAD / GBM);        // (79,79); guards trim to 10000
    gemm_mfma_kernel<1, 0><<<gFC, 256, 0, stream>>>(h3bb, fcWt, fcb, out, N, N, 128);
}

// Round 6
// 657.373 us; speedup vs baseline: 1.0666x; 1.0666x over previous
//
#include <hip/hip_runtime.h>
#include <hip/hip_bf16.h>
#include <math.h>

#define N_NODES 10000
#define N_EDGES 100000
#define F_IN    128
#define CH      120
#define NH      16
#define NEG_SLOPE 0.2f
#define MPAD    10112          // N padded to multiple of 128

typedef unsigned short ushort_t;
typedef short short8 __attribute__((ext_vector_type(8)));
typedef float floatx4 __attribute__((ext_vector_type(4)));

__device__ inline ushort_t f2b(float f) {            // fp32->bf16 RNE
    unsigned u = __float_as_uint(f);
    unsigned r = (u + 0x7fffu + ((u >> 16) & 1u)) >> 16;
    return (ushort_t)r;
}
__device__ inline float b2f(ushort_t u) { return __uint_as_float(((unsigned)u) << 16); }

// async global->LDS, 16B per lane (dest = wave-uniform base + lane*16)
__device__ __forceinline__ void gload16(const ushort_t* g, ushort_t* l) {
    __builtin_amdgcn_global_load_lds(
        (const __attribute__((address_space(1))) unsigned int*)g,
        (__attribute__((address_space(3))) unsigned int*)l,
        16, 0, 0);
}

// ======================== bf16 MFMA GEMM (m97 structure) ========================
// C[M,Nn] = A[M,K] @ Bt[Nn,K]^T. A stride K, Bt stride K; K multiple of 32.
#define GBM 128
#define GBN 128
#define GBK 32

template<int ACT, int OUTBF>   // ACT: 0 none 1 relu; OUTBF: bf16 out?
__global__ __launch_bounds__(256) void gemm_mfma_kernel(
    const ushort_t* __restrict__ A, const ushort_t* __restrict__ Bt,
    const float* __restrict__ bias, void* __restrict__ Cv,
    int M, int Nn, int K)
{
    __shared__ ushort_t As[GBM * GBK];
    __shared__ ushort_t Bs[GBN * GBK];
    const int t = threadIdx.x;
    const int lane = t & 63;
    const int wid = t >> 6;
    const int wr = wid >> 1, wc = wid & 1;
    const int row0 = blockIdx.y * GBM, col0 = blockIdx.x * GBN;
    const int laneRow = lane & 15;
    const int laneK   = (lane >> 4) * 8;
    const int srow = lane >> 2;
    const int skq  = (lane & 3) * 8;

    floatx4 acc[4][4];
#pragma unroll
    for (int m = 0; m < 4; ++m)
#pragma unroll
        for (int n = 0; n < 4; ++n)
            acc[m][n] = (floatx4){0.f, 0.f, 0.f, 0.f};

    for (int k0 = 0; k0 < K; k0 += GBK) {
#pragma unroll
        for (int i = 0; i < 2; ++i) {
            int ai = wid * 2 + i;
            gload16(A + (size_t)(row0 + ai * 16 + srow) * K + k0 + skq,
                    &As[ai * 512]);
        }
#pragma unroll
        for (int i = 0; i < 2; ++i) {
            int bi = wid * 2 + i;
            gload16(Bt + (size_t)(col0 + bi * 16 + srow) * K + k0 + skq,
                    &Bs[bi * 512]);
        }
        __syncthreads();

        short8 af[4], bf[4];
#pragma unroll
        for (int m = 0; m < 4; ++m)
            af[m] = *reinterpret_cast<const short8*>(
                &As[(wr * 64 + m * 16 + laneRow) * GBK + laneK]);
#pragma unroll
        for (int n = 0; n < 4; ++n)
            bf[n] = *reinterpret_cast<const short8*>(
                &Bs[(wc * 64 + n * 16 + laneRow) * GBK + laneK]);
#pragma unroll
        for (int m = 0; m < 4; ++m)
#pragma unroll
            for (int n = 0; n < 4; ++n)
                acc[m][n] = __builtin_amdgcn_mfma_f32_16x16x32_bf16(
                    af[m], bf[n], acc[m][n], 0, 0, 0);
        __syncthreads();
    }

    const int orow = (lane >> 4) * 4;   // C/D: col=lane&15, row=(lane>>4)*4+j
#pragma unroll
    for (int m = 0; m < 4; ++m) {
#pragma unroll
        for (int n = 0; n < 4; ++n) {
            int gc = col0 + wc * 64 + n * 16 + laneRow;
            if (gc >= Nn) continue;
            float bv = bias ? bias[gc] : 0.f;
#pragma unroll
            for (int j = 0; j < 4; ++j) {
                int gr = row0 + wr * 64 + m * 16 + orow + j;
                if (gr >= M) continue;
                float v = acc[m][n][j] + bv;
                if (ACT == 1) v = fmaxf(v, 0.f);
                if (OUTBF) ((ushort_t*)Cv)[(size_t)gr * Nn + gc] = f2b(v);
                else       ((float*)Cv)   [(size_t)gr * Nn + gc] = v;
            }
        }
    }
}

// ---- split-K variant: fp32 atomicAdd into C (C pre-zeroed), no bias/act
__global__ __launch_bounds__(256) void gemm_splitk_kernel(
    const ushort_t* __restrict__ A, const ushort_t* __restrict__ Bt,
    float* __restrict__ C, int M, int Nn, int K, int KS)
{
    __shared__ ushort_t As[GBM * GBK];
    __shared__ ushort_t Bs[GBN * GBK];
    const int t = threadIdx.x;
    const int lane = t & 63;
    const int wid = t >> 6;
    const int wr = wid >> 1, wc = wid & 1;
    const int row0 = blockIdx.y * GBM, col0 = blockIdx.x * GBN;
    const int kbeg = blockIdx.z * KS, kend = kbeg + KS;
    const int laneRow = lane & 15;
    const int laneK   = (lane >> 4) * 8;
    const int srow = lane >> 2;
    const int skq  = (lane & 3) * 8;

    floatx4 acc[4][4];
#pragma unroll
    for (int m = 0; m < 4; ++m)
#pragma unroll
        for (int n = 0; n < 4; ++n)
            acc[m][n] = (floatx4){0.f, 0.f, 0.f, 0.f};

    for (int k0 = kbeg; k0 < kend; k0 += GBK) {
#pragma unroll
        for (int i = 0; i < 2; ++i) {
            int ai = wid * 2 + i;
            gload16(A + (size_t)(row0 + ai * 16 + srow) * K + k0 + skq,
                    &As[ai * 512]);
        }
#pragma unroll
        for (int i = 0; i < 2; ++i) {
            int bi = wid * 2 + i;
            gload16(Bt + (size_t)(col0 + bi * 16 + srow) * K + k0 + skq,
                    &Bs[bi * 512]);
        }
        __syncthreads();

        short8 af[4], bf[4];
#pragma unroll
        for (int m = 0; m < 4; ++m)
            af[m] = *reinterpret_cast<const short8*>(
                &As[(wr * 64 + m * 16 + laneRow) * GBK + laneK]);
#pragma unroll
        for (int n = 0; n < 4; ++n)
            bf[n] = *reinterpret_cast<const short8*>(
                &Bs[(wc * 64 + n * 16 + laneRow) * GBK + laneK]);
#pragma unroll
        for (int m = 0; m < 4; ++m)
#pragma unroll
            for (int n = 0; n < 4; ++n)
                acc[m][n] = __builtin_amdgcn_mfma_f32_16x16x32_bf16(
                    af[m], bf[n], acc[m][n], 0, 0, 0);
        __syncthreads();
    }

    const int orow = (lane >> 4) * 4;
#pragma unroll
    for (int m = 0; m < 4; ++m) {
#pragma unroll
        for (int n = 0; n < 4; ++n) {
            int gc = col0 + wc * 64 + n * 16 + laneRow;
            if (gc >= Nn) continue;
#pragma unroll
            for (int j = 0; j < 4; ++j) {
                int gr = row0 + wr * 64 + m * 16 + orow + j;
                if (gr >= M) continue;
                atomicAdd(&C[(size_t)gr * Nn + gc], acc[m][n][j]);
            }
        }
    }
}

// ======================== transpose + f32->bf16 ========================
__global__ __launch_bounds__(256) void transpose_b_kernel(
    const float* __restrict__ in, ushort_t* __restrict__ out,
    int R, int Cc, int Kpad)
{
    __shared__ float tile[32][33];
    const int tx = threadIdx.x & 31, ty = threadIdx.x >> 5;
    const int k0 = blockIdx.x * 32, n0 = blockIdx.y * 32;
#pragma unroll
    for (int i = 0; i < 4; ++i) {
        int r = k0 + ty + i * 8, c = n0 + tx;
        tile[ty + i * 8][tx] = (r < R && c < Cc) ? in[(size_t)r * Cc + c] : 0.f;
    }
    __syncthreads();
#pragma unroll
    for (int i = 0; i < 4; ++i) {
        int orow = n0 + ty + i * 8, ocol = k0 + tx;
        out[(size_t)orow * Kpad + ocol] = f2b(tile[tx][ty + i * 8]);
    }
}

// ======================== conversions ========================
__global__ void f2b_kernel(const float* __restrict__ in, ushort_t* __restrict__ out, int n)
{
    int i4 = (blockIdx.x * blockDim.x + threadIdx.x) * 4;
    if (i4 + 4 <= n) {
        float4 v = *reinterpret_cast<const float4*>(in + i4);
        ushort4 o = make_ushort4(f2b(v.x), f2b(v.y), f2b(v.z), f2b(v.w));
        *reinterpret_cast<ushort4*>(out + i4) = o;
    } else {
        for (; i4 < n; ++i4) out[i4] = f2b(in[i4]);
    }
}

// ======================== edge-index dtype handling ========================
__global__ void detect_kernel(const int* __restrict__ w, int nwords, int* flag)
{
    int i = blockIdx.x * blockDim.x + threadIdx.x;
    int odd = 2 * i + 1;
    if (odd < nwords && w[odd] != 0) atomicOr(flag, 1);
}

// decode edges + dst histogram in one pass
__global__ void convert_hist_kernel(const int* __restrict__ w, const int* __restrict__ flag,
                                    int* __restrict__ src, int* __restrict__ dst,
                                    int* __restrict__ deg, int E)
{
    int i = blockIdx.x * blockDim.x + threadIdx.x;
    if (i >= E) return;
    int s, d;
    if (*flag == 0) { s = w[2 * i]; d = w[2 * E + 2 * i]; }
    else            { s = w[i];     d = w[E + i]; }
    src[i] = s; dst[i] = d;
    atomicAdd(deg + d, 1);
}

// ======================== CSR build ========================
#define SCAN_T 1024
__global__ __launch_bounds__(SCAN_T) void scan_kernel(
    const int* __restrict__ deg, int* __restrict__ off, int n)
{
    __shared__ int part[SCAN_T];
    int t = threadIdx.x;
    int per = (n + SCAN_T - 1) / SCAN_T;
    int b0 = t * per, b1 = min(b0 + per, n);
    int s = 0;
    for (int i = b0; i < b1; ++i) s += deg[i];
    part[t] = s;
    __syncthreads();
    for (int d = 1; d < SCAN_T; d <<= 1) {
        int v = (t >= d) ? part[t - d] : 0;
        __syncthreads();
        part[t] += v;
        __syncthreads();
    }
    int run = (t == 0) ? 0 : part[t - 1];
    for (int i = b0; i < b1; ++i) { off[i] = run; run += deg[i]; }
    if (t == SCAN_T - 1) off[n] = run;
}

__global__ void scatter_kernel(const int* __restrict__ src, const int* __restrict__ dst,
                               const int* __restrict__ off, int* __restrict__ cnt,
                               int* __restrict__ srcs, int E)
{
    int i = blockIdx.x * blockDim.x + threadIdx.x;
    if (i >= E) return;
    int d = dst[i];
    int pos = off[d] + atomicAdd(cnt + d, 1);
    srcs[pos] = src[i];
}

// ======================== attention logits ========================
__global__ void al_bf16_kernel(const ushort_t* __restrict__ h,
                               const float* __restrict__ a_s, const float* __restrict__ a_d,
                               float* __restrict__ als, float* __restrict__ ald,
                               int Nn, int Hh, int Cc)
{
    int wid  = (blockIdx.x * blockDim.x + threadIdx.x) >> 6;
    int lane = threadIdx.x & 63;
    if (wid >= Nn * Hh) return;
    int n = wid / Hh, hh = wid - n * Hh;
    const ushort_t* hp = h + (size_t)n * Hh * Cc + hh * Cc;
    float s1 = 0.f, s2 = 0.f;
    int c = lane * 2;
    if (c < Cc) {
        unsigned w = *reinterpret_cast<const unsigned*>(hp + c);
        float f0 = b2f((ushort_t)(w & 0xffffu)), f1 = b2f((ushort_t)(w >> 16));
        float2 as2 = *reinterpret_cast<const float2*>(a_s + hh * Cc + c);
        float2 ad2 = *reinterpret_cast<const float2*>(a_d + hh * Cc + c);
        s1 = f0 * as2.x + f1 * as2.y;
        s2 = f0 * ad2.x + f1 * ad2.y;
    }
#pragma unroll
    for (int o = 32; o; o >>= 1) {
        s1 += __shfl_down(s1, o);
        s2 += __shfl_down(s2, o);
    }
    if (lane == 0) { als[wid] = s1; ald[wid] = s2; }
}

// ======================== fused CSR segment softmax ========================
template<int HH, int LOGH>
__global__ void softmax_csr_kernel(const float* __restrict__ als,
                                   const float* __restrict__ ald,
                                   const int* __restrict__ off,
                                   const int* __restrict__ srcs,
                                   float* __restrict__ ebuf, int Nn)
{
    const int d = blockIdx.x * (blockDim.x >> 6) + (threadIdx.x >> 6);
    if (d >= Nn) return;
    const int lane = threadIdx.x & 63;
    const int h = lane & (HH - 1);
    const int j = lane >> LOGH;
    const int JS = 64 >> LOGH;
    const int start = off[d], end = off[d + 1];
    const float aldv = ald[d * HH + h];
    float m = -1e30f, ssum = 0.f;
    for (int base = start; base < end; base += JS) {
        int e = base + j;
        float v = -1e30f;
        if (e < end) {
            int s = srcs[e];
            float x = als[s * HH + h] + aldv;
            v = (x > 0.f) ? x : NEG_SLOPE * x;
            ebuf[(size_t)e * HH + h] = v;
        }
        float cm = v;
#pragma unroll
        for (int o = HH; o <= 32; o <<= 1) cm = fmaxf(cm, __shfl_xor(cm, o));
        float mnew = fmaxf(m, cm);
        float ex = (e < end) ? __expf(v - mnew) : 0.f;
#pragma unroll
        for (int o = HH; o <= 32; o <<= 1) ex += __shfl_xor(ex, o);
        ssum = ssum * __expf(m - mnew) + ex;
        m = mnew;
    }
    float rs = 1.f / ssum;
    for (int base = start; base < end; base += JS) {
        int e = base + j;
        if (e < end) {
            float v = ebuf[(size_t)e * HH + h];
            ebuf[(size_t)e * HH + h] = __expf(v - m) * rs;
        }
    }
}

// ======================== aggregation: block per node, no LDS/syncs ========================
// 240 active threads, thread t owns cols [t*8, t*8+8). srcs[e] load is a
// same-address L1 broadcast; alpha read hits one cacheline per edge.
template<int ACT>
__global__ __launch_bounds__(256) void agg_node_kernel(
    const ushort_t* __restrict__ h, const float* __restrict__ ebuf,
    const int* __restrict__ off, const int* __restrict__ srcs,
    const float* __restrict__ bias, ushort_t* __restrict__ outb)
{
    const int d = blockIdx.x;
    const int t = threadIdx.x;
    if (t >= 240) return;
    const int col = t * 8;
    const int head = col / CH;       // 8-elem chunk stays in one head (120%8==0)
    const int start = off[d], end = off[d + 1];
    float acc[8] = {0.f, 0.f, 0.f, 0.f, 0.f, 0.f, 0.f, 0.f};
    int e = start;
    for (; e + 2 <= end; e += 2) {
        int s0 = srcs[e], s1 = srcs[e + 1];
        float a0 = ebuf[(size_t)e * NH + head];
        float a1 = ebuf[(size_t)(e + 1) * NH + head];
        short8 v0 = *reinterpret_cast<const short8*>(h + (size_t)s0 * 1920 + col);
        short8 v1 = *reinterpret_cast<const short8*>(h + (size_t)s1 * 1920 + col);
#pragma unroll
        for (int k = 0; k < 8; ++k)
            acc[k] = fmaf(b2f((ushort_t)v1[k]), a1,
                          fmaf(b2f((ushort_t)v0[k]), a0, acc[k]));
    }
    if (e < end) {
        int s0 = srcs[e];
        float a0 = ebuf[(size_t)e * NH + head];
        short8 v0 = *reinterpret_cast<const short8*>(h + (size_t)s0 * 1920 + col);
#pragma unroll
        for (int k = 0; k < 8; ++k)
            acc[k] = fmaf(b2f((ushort_t)v0[k]), a0, acc[k]);
    }
    short8 o;
#pragma unroll
    for (int k = 0; k < 8; ++k) {
        float v = acc[k] + bias[col + k];
        if (ACT) v = (v > 0.f) ? v : expm1f(v);
        o[k] = (short)f2b(v);
    }
    *reinterpret_cast<short8*>(outb + (size_t)d * 1920 + col) = o;
}

// H=1, F=120 variant: 60 lanes x short2, out stride 128 (padded FC input)
__global__ __launch_bounds__(64) void agg_node1_kernel(
    const ushort_t* __restrict__ h, const float* __restrict__ ebuf,
    const int* __restrict__ off, const int* __restrict__ srcs,
    const float* __restrict__ bias, ushort_t* __restrict__ outb)
{
    const int d = blockIdx.x;
    const int t = threadIdx.x;
    if (t >= 60) return;
    const int col = t * 2;
    const int start = off[d], end = off[d + 1];
    float acc0 = 0.f, acc1 = 0.f;
    for (int e = start; e < end; ++e) {
        int s = srcs[e];
        float a = ebuf[e];
        unsigned w = *reinterpret_cast<const unsigned*>(h + (size_t)s * CH + col);
        acc0 = fmaf(b2f((ushort_t)(w & 0xffffu)), a, acc0);
        acc1 = fmaf(b2f((ushort_t)(w >> 16)), a, acc1);
    }
    float v0 = acc0 + bias[col], v1 = acc1 + bias[col + 1];
    unsigned o = (unsigned)f2b(v0) | ((unsigned)f2b(v1) << 16);
    *reinterpret_cast<unsigned*>(outb + (size_t)d * 128 + col) = o;
}

// ======================== launch ========================
extern "C" void kernel_launch(void* const* d_in, const int* in_sizes, int n_in,
                              void* d_out, int out_size, void* d_ws, size_t ws_size,
                              hipStream_t stream)
{
    const float* x   = (const float*)d_in[0];
    const int*   ei  = (const int*)  d_in[1];
    const float* W1  = (const float*)d_in[2];
    const float* a1s = (const float*)d_in[3];
    const float* a1d = (const float*)d_in[4];
    const float* b1  = (const float*)d_in[5];
    const float* W2  = (const float*)d_in[6];
    const float* a2s = (const float*)d_in[7];
    const float* a2d = (const float*)d_in[8];
    const float* b2  = (const float*)d_in[9];
    const float* W3  = (const float*)d_in[10];
    const float* a3s = (const float*)d_in[11];
    const float* a3d = (const float*)d_in[12];
    const float* b3  = (const float*)d_in[13];
    const float* fcW = (const float*)d_in[14];
    const float* fcb = (const float*)d_in[15];

    float* out = (float*)d_out;
    const int N = N_NODES, E = N_EDGES;
    const int F16 = NH * CH;                 // 1920

    // ---- scratch inside d_out (FC overwrites all of d_out last)
    ushort_t* hraw  = (ushort_t*)out;                    // [MPAD][1920]
    ushort_t* hagg  = hraw + (size_t)MPAD * F16;         // [MPAD][1920]
    ushort_t* xb    = hagg + (size_t)MPAD * F16;         // [MPAD][128]
    ushort_t* W1t   = xb   + (size_t)MPAD * F_IN;        // [1920][128]
    ushort_t* W2t   = W1t  + (size_t)F16 * F_IN;         // [1920][1920]
    ushort_t* W3t   = W2t  + (size_t)F16 * F16;          // [128][1920]
    ushort_t* h3raw = W3t  + (size_t)128 * F16;          // [N][120] bf16
    float*    h3tmp = (float*)(h3raw + (size_t)N * CH);  // [N][120] fp32 (split-K)
    float*    als   = h3tmp + (size_t)N * CH;
    float*    ald   = als + (size_t)N * NH;
    float*    ebuf  = ald + (size_t)N * NH;              // [E][16] sorted alpha
    int*      srcv  = (int*)(ebuf + (size_t)E * NH);
    int*      dstv  = srcv + E;
    int*      srcs  = dstv + E;
    int*      flag  = srcs + E;
    int*      deg   = flag + 1;                          // [N]
    int*      offv  = deg + N;                           // [N+1]
    int*      cnt   = offv + N + 1;                      // [N]
    // ---- d_ws: FC inputs (read while FC writes d_out)
    ushort_t* h3bb = (ushort_t*)d_ws;                    // [MPAD][128]
    ushort_t* fcWt = h3bb + (size_t)MPAD * 128;          // [MPAD][128]

    // ---- edge decode + CSR build
    hipMemsetAsync(flag, 0, sizeof(int), stream);
    hipMemsetAsync(deg, 0, (size_t)N * 4, stream);
    hipMemsetAsync(cnt, 0, (size_t)N * 4, stream);
    detect_kernel      <<<(E + 255) / 256, 256, 0, stream>>>(ei, 2 * E, flag);
    convert_hist_kernel<<<(E + 255) / 256, 256, 0, stream>>>(ei, flag, srcv, dstv, deg, E);
    scan_kernel        <<<1, SCAN_T, 0, stream>>>(deg, offv, N);
    scatter_kernel     <<<(E + 255) / 256, 256, 0, stream>>>(srcv, dstv, offv, cnt, srcs, E);

    // ---- input/weight prep
    f2b_kernel<<<(N * F_IN / 4 + 255) / 256, 256, 0, stream>>>(x, xb, N * F_IN);
    dim3 tb(256);
    transpose_b_kernel<<<dim3(F_IN / 32, F16 / 32), tb, 0, stream>>>(W1, W1t, F_IN, F16, F_IN);
    transpose_b_kernel<<<dim3(F16 / 32, F16 / 32), tb, 0, stream>>>(W2, W2t, F16, F16, F16);
    transpose_b_kernel<<<dim3(F16 / 32, 128 / 32), tb, 0, stream>>>(W3, W3t, F16, CH, F16);
    transpose_b_kernel<<<dim3(128 / 32, MPAD / 32), tb, 0, stream>>>(fcW, fcWt, CH, N, 128);

    dim3 gBig(F16 / GBN, MPAD / GBM);        // (15,79)

    // =============== layer 1 ===============
    gemm_mfma_kernel<0, 1><<<gBig, 256, 0, stream>>>(xb, W1t, nullptr, hraw, N, F16, F_IN);
    al_bf16_kernel<<<(N * NH + 3) / 4, 256, 0, stream>>>(hraw, a1s, a1d, als, ald, N, NH, CH);
    softmax_csr_kernel<16, 4><<<(N + 3) / 4, 256, 0, stream>>>(als, ald, offv, srcs, ebuf, N);
    agg_node_kernel<1><<<N, 256, 0, stream>>>(hraw, ebuf, offv, srcs, b1, hagg);

    // =============== layer 2 ===============
    gemm_mfma_kernel<0, 1><<<gBig, 256, 0, stream>>>(hagg, W2t, nullptr, hraw, N, F16, F16);
    al_bf16_kernel<<<(N * NH + 3) / 4, 256, 0, stream>>>(hraw, a2s, a2d, als, ald, N, NH, CH);
    softmax_csr_kernel<16, 4><<<(N + 3) / 4, 256, 0, stream>>>(als, ald, offv, srcs, ebuf, N);
    agg_node_kernel<1><<<N, 256, 0, stream>>>(hraw, ebuf, offv, srcs, b2, hagg);

    // =============== layer 3 (H=1), split-K GEMM ===============
    hipMemsetAsync(h3tmp, 0, (size_t)N * CH * 4, stream);
    dim3 gL3(1, MPAD / GBM, 6);              // K split 1920 -> 6 x 320
    gemm_splitk_kernel<<<gL3, 256, 0, stream>>>(hagg, W3t, h3tmp, N, CH, F16, 320);
    f2b_kernel<<<(N * CH / 4 + 255) / 256, 256, 0, stream>>>(h3tmp, h3raw, N * CH);
    al_bf16_kernel<<<(N + 3) / 4, 256, 0, stream>>>(h3raw, a3s, a3d, als, ald, N, 1, CH);
    softmax_csr_kernel<1, 0><<<(N + 3) / 4, 256, 0, stream>>>(als, ald, offv, srcs, ebuf, N);
    agg_node1_kernel<<<N, 64, 0, stream>>>(h3raw, ebuf, offv, srcs, b3, h3bb);

    // =============== FC + ReLU ===============
    dim3 gFC(MPAD / GBN, MPAD / GBM);        // (79,79); guards trim to 10000
    gemm_mfma_kernel<1, 0><<<gFC, 256, 0, stream>>>(h3bb, fcWt, fcb, out, N, N, 128);
}

// Round 7
// 619.042 us; speedup vs baseline: 1.1327x; 1.0619x over previous
//
#include <hip/hip_runtime.h>
#include <hip/hip_bf16.h>
#include <math.h>

#define N_NODES 10000
#define N_EDGES 100000
#define F_IN    128
#define CH      120
#define NH      16
#define NEG_SLOPE 0.2f
#define MPAD    10112          // N padded to multiple of 128

typedef unsigned short ushort_t;
typedef short short8 __attribute__((ext_vector_type(8)));
typedef float floatx4 __attribute__((ext_vector_type(4)));

__device__ inline ushort_t f2b(float f) {            // fp32->bf16 RNE
    unsigned u = __float_as_uint(f);
    unsigned r = (u + 0x7fffu + ((u >> 16) & 1u)) >> 16;
    return (ushort_t)r;
}
__device__ inline float b2f(ushort_t u) { return __uint_as_float(((unsigned)u) << 16); }

// async global->LDS, 16B per lane (dest = wave-uniform base + lane*16)
__device__ __forceinline__ void gload16(const ushort_t* g, ushort_t* l) {
    __builtin_amdgcn_global_load_lds(
        (const __attribute__((address_space(1))) unsigned int*)g,
        (__attribute__((address_space(3))) unsigned int*)l,
        16, 0, 0);
}

// ======================== bf16 MFMA GEMM (m97 structure) ========================
// C[M,Nn] = A[M,K] @ Bt[Nn,K]^T. A stride K, Bt stride K; K multiple of 32.
#define GBM 128
#define GBN 128
#define GBK 32

template<int ACT, int OUTBF>   // ACT: 0 none 1 relu; OUTBF: bf16 out?
__global__ __launch_bounds__(256) void gemm_mfma_kernel(
    const ushort_t* __restrict__ A, const ushort_t* __restrict__ Bt,
    const float* __restrict__ bias, void* __restrict__ Cv,
    int M, int Nn, int K)
{
    __shared__ ushort_t As[GBM * GBK];
    __shared__ ushort_t Bs[GBN * GBK];
    const int t = threadIdx.x;
    const int lane = t & 63;
    const int wid = t >> 6;
    const int wr = wid >> 1, wc = wid & 1;
    const int row0 = blockIdx.y * GBM, col0 = blockIdx.x * GBN;
    const int laneRow = lane & 15;
    const int laneK   = (lane >> 4) * 8;
    const int srow = lane >> 2;
    const int skq  = (lane & 3) * 8;

    floatx4 acc[4][4];
#pragma unroll
    for (int m = 0; m < 4; ++m)
#pragma unroll
        for (int n = 0; n < 4; ++n)
            acc[m][n] = (floatx4){0.f, 0.f, 0.f, 0.f};

    for (int k0 = 0; k0 < K; k0 += GBK) {
#pragma unroll
        for (int i = 0; i < 2; ++i) {
            int ai = wid * 2 + i;
            gload16(A + (size_t)(row0 + ai * 16 + srow) * K + k0 + skq,
                    &As[ai * 512]);
        }
#pragma unroll
        for (int i = 0; i < 2; ++i) {
            int bi = wid * 2 + i;
            gload16(Bt + (size_t)(col0 + bi * 16 + srow) * K + k0 + skq,
                    &Bs[bi * 512]);
        }
        __syncthreads();

        short8 af[4], bf[4];
#pragma unroll
        for (int m = 0; m < 4; ++m)
            af[m] = *reinterpret_cast<const short8*>(
                &As[(wr * 64 + m * 16 + laneRow) * GBK + laneK]);
#pragma unroll
        for (int n = 0; n < 4; ++n)
            bf[n] = *reinterpret_cast<const short8*>(
                &Bs[(wc * 64 + n * 16 + laneRow) * GBK + laneK]);
#pragma unroll
        for (int m = 0; m < 4; ++m)
#pragma unroll
            for (int n = 0; n < 4; ++n)
                acc[m][n] = __builtin_amdgcn_mfma_f32_16x16x32_bf16(
                    af[m], bf[n], acc[m][n], 0, 0, 0);
        __syncthreads();
    }

    const int orow = (lane >> 4) * 4;   // C/D: col=lane&15, row=(lane>>4)*4+j
#pragma unroll
    for (int m = 0; m < 4; ++m) {
#pragma unroll
        for (int n = 0; n < 4; ++n) {
            int gc = col0 + wc * 64 + n * 16 + laneRow;
            if (gc >= Nn) continue;
            float bv = bias ? bias[gc] : 0.f;
#pragma unroll
            for (int j = 0; j < 4; ++j) {
                int gr = row0 + wr * 64 + m * 16 + orow + j;
                if (gr >= M) continue;
                float v = acc[m][n][j] + bv;
                if (ACT == 1) v = fmaxf(v, 0.f);
                if (OUTBF) ((ushort_t*)Cv)[(size_t)gr * Nn + gc] = f2b(v);
                else       ((float*)Cv)   [(size_t)gr * Nn + gc] = v;
            }
        }
    }
}

// ---- split-K variant: fp32 atomicAdd into C (C pre-zeroed), no bias/act
__global__ __launch_bounds__(256) void gemm_splitk_kernel(
    const ushort_t* __restrict__ A, const ushort_t* __restrict__ Bt,
    float* __restrict__ C, int M, int Nn, int K, int KS)
{
    __shared__ ushort_t As[GBM * GBK];
    __shared__ ushort_t Bs[GBN * GBK];
    const int t = threadIdx.x;
    const int lane = t & 63;
    const int wid = t >> 6;
    const int wr = wid >> 1, wc = wid & 1;
    const int row0 = blockIdx.y * GBM, col0 = blockIdx.x * GBN;
    const int kbeg = blockIdx.z * KS, kend = kbeg + KS;
    const int laneRow = lane & 15;
    const int laneK   = (lane >> 4) * 8;
    const int srow = lane >> 2;
    const int skq  = (lane & 3) * 8;

    floatx4 acc[4][4];
#pragma unroll
    for (int m = 0; m < 4; ++m)
#pragma unroll
        for (int n = 0; n < 4; ++n)
            acc[m][n] = (floatx4){0.f, 0.f, 0.f, 0.f};

    for (int k0 = kbeg; k0 < kend; k0 += GBK) {
#pragma unroll
        for (int i = 0; i < 2; ++i) {
            int ai = wid * 2 + i;
            gload16(A + (size_t)(row0 + ai * 16 + srow) * K + k0 + skq,
                    &As[ai * 512]);
        }
#pragma unroll
        for (int i = 0; i < 2; ++i) {
            int bi = wid * 2 + i;
            gload16(Bt + (size_t)(col0 + bi * 16 + srow) * K + k0 + skq,
                    &Bs[bi * 512]);
        }
        __syncthreads();

        short8 af[4], bf[4];
#pragma unroll
        for (int m = 0; m < 4; ++m)
            af[m] = *reinterpret_cast<const short8*>(
                &As[(wr * 64 + m * 16 + laneRow) * GBK + laneK]);
#pragma unroll
        for (int n = 0; n < 4; ++n)
            bf[n] = *reinterpret_cast<const short8*>(
                &Bs[(wc * 64 + n * 16 + laneRow) * GBK + laneK]);
#pragma unroll
        for (int m = 0; m < 4; ++m)
#pragma unroll
            for (int n = 0; n < 4; ++n)
                acc[m][n] = __builtin_amdgcn_mfma_f32_16x16x32_bf16(
                    af[m], bf[n], acc[m][n], 0, 0, 0);
        __syncthreads();
    }

    const int orow = (lane >> 4) * 4;
#pragma unroll
    for (int m = 0; m < 4; ++m) {
#pragma unroll
        for (int n = 0; n < 4; ++n) {
            int gc = col0 + wc * 64 + n * 16 + laneRow;
            if (gc >= Nn) continue;
#pragma unroll
            for (int j = 0; j < 4; ++j) {
                int gr = row0 + wr * 64 + m * 16 + orow + j;
                if (gr >= M) continue;
                atomicAdd(&C[(size_t)gr * Nn + gc], acc[m][n][j]);
            }
        }
    }
}

// ---- FC kernel: bias+ReLU fused, LDS-staged coalesced float4 C-writes
__global__ __launch_bounds__(256) void gemm_fc_kernel(
    const ushort_t* __restrict__ A, const ushort_t* __restrict__ Bt,
    const float* __restrict__ bias, float* __restrict__ C,
    int M, int Nn, int K)
{
    __shared__ ushort_t As[GBM * GBK];
    __shared__ ushort_t Bs[GBN * GBK];
    __shared__ float ct[32][132];
    const int t = threadIdx.x;
    const int lane = t & 63;
    const int wid = t >> 6;
    const int wr = wid >> 1, wc = wid & 1;
    const int row0 = blockIdx.y * GBM, col0 = blockIdx.x * GBN;
    const int laneRow = lane & 15;
    const int laneK   = (lane >> 4) * 8;
    const int srow = lane >> 2;
    const int skq  = (lane & 3) * 8;

    floatx4 acc[4][4];
#pragma unroll
    for (int m = 0; m < 4; ++m)
#pragma unroll
        for (int n = 0; n < 4; ++n)
            acc[m][n] = (floatx4){0.f, 0.f, 0.f, 0.f};

    for (int k0 = 0; k0 < K; k0 += GBK) {
#pragma unroll
        for (int i = 0; i < 2; ++i) {
            int ai = wid * 2 + i;
            gload16(A + (size_t)(row0 + ai * 16 + srow) * K + k0 + skq,
                    &As[ai * 512]);
        }
#pragma unroll
        for (int i = 0; i < 2; ++i) {
            int bi = wid * 2 + i;
            gload16(Bt + (size_t)(col0 + bi * 16 + srow) * K + k0 + skq,
                    &Bs[bi * 512]);
        }
        __syncthreads();

        short8 af[4], bf[4];
#pragma unroll
        for (int m = 0; m < 4; ++m)
            af[m] = *reinterpret_cast<const short8*>(
                &As[(wr * 64 + m * 16 + laneRow) * GBK + laneK]);
#pragma unroll
        for (int n = 0; n < 4; ++n)
            bf[n] = *reinterpret_cast<const short8*>(
                &Bs[(wc * 64 + n * 16 + laneRow) * GBK + laneK]);
#pragma unroll
        for (int m = 0; m < 4; ++m)
#pragma unroll
            for (int n = 0; n < 4; ++n)
                acc[m][n] = __builtin_amdgcn_mfma_f32_16x16x32_bf16(
                    af[m], bf[n], acc[m][n], 0, 0, 0);
        __syncthreads();
    }

    const int orow = (lane >> 4) * 4;
#pragma unroll
    for (int m = 0; m < 4; ++m) {
        __syncthreads();
#pragma unroll
        for (int n = 0; n < 4; ++n)
#pragma unroll
            for (int j = 0; j < 4; ++j)
                ct[wr * 16 + orow + j][wc * 64 + n * 16 + laneRow] = acc[m][n][j];
        __syncthreads();
#pragma unroll
        for (int i = 0; i < 4; ++i) {
            int idx = t + i * 256;              // 0..1023
            int lr = idx >> 5, lc = (idx & 31) * 4;
            int gr = row0 + (lr & 15) + m * 16 + (lr >> 4) * 64;
            if (gr >= M) continue;
            int gc = col0 + lc;
            float4 v = *reinterpret_cast<const float4*>(&ct[lr][lc]);
            if (gc + 4 <= Nn) {
                float4 b4 = *reinterpret_cast<const float4*>(bias + gc);
                v.x = fmaxf(v.x + b4.x, 0.f);
                v.y = fmaxf(v.y + b4.y, 0.f);
                v.z = fmaxf(v.z + b4.z, 0.f);
                v.w = fmaxf(v.w + b4.w, 0.f);
                *reinterpret_cast<float4*>(C + (size_t)gr * Nn + gc) = v;
            } else {
                float vv[4] = {v.x, v.y, v.z, v.w};
#pragma unroll
                for (int q = 0; q < 4; ++q)
                    if (gc + q < Nn)
                        C[(size_t)gr * Nn + gc + q] = fmaxf(vv[q] + bias[gc + q], 0.f);
            }
        }
    }
}

// ======================== merged weight prep (4 transposes) ========================
// out[Npad][Kpad] = in[k][n] (bf16), zero-padded.
__global__ __launch_bounds__(256) void prep4_kernel(
    const float* __restrict__ W1, const float* __restrict__ W2,
    const float* __restrict__ W3, const float* __restrict__ fcW,
    ushort_t* __restrict__ W1t, ushort_t* __restrict__ W2t,
    ushort_t* __restrict__ W3t, ushort_t* __restrict__ fcWt)
{
    int b = blockIdx.x;
    const float* in; ushort_t* outp; int R, Cc, Kpad, tilesK;
    if (b < 240)       { in = W1;  outp = W1t;  R = 128;  Cc = 1920;  Kpad = 128;  tilesK = 4; }
    else if (b < 3840) { b -= 240;  in = W2;  outp = W2t;  R = 1920; Cc = 1920;  Kpad = 1920; tilesK = 60; }
    else if (b < 4080) { b -= 3840; in = W3;  outp = W3t;  R = 1920; Cc = 120;   Kpad = 1920; tilesK = 60; }
    else               { b -= 4080; in = fcW; outp = fcWt; R = 120;  Cc = 10000; Kpad = 128;  tilesK = 4; }
    const int k0 = (b % tilesK) * 32, n0 = (b / tilesK) * 32;
    __shared__ float tile[32][33];
    const int tx = threadIdx.x & 31, ty = threadIdx.x >> 5;
#pragma unroll
    for (int i = 0; i < 4; ++i) {
        int r = k0 + ty + i * 8, c = n0 + tx;
        tile[ty + i * 8][tx] = (r < R && c < Cc) ? in[(size_t)r * Cc + c] : 0.f;
    }
    __syncthreads();
#pragma unroll
    for (int i = 0; i < 4; ++i) {
        int orow = n0 + ty + i * 8, ocol = k0 + tx;
        outp[(size_t)orow * Kpad + ocol] = f2b(tile[tx][ty + i * 8]);
    }
}

// ======================== conversions ========================
__global__ void f2b_kernel(const float* __restrict__ in, ushort_t* __restrict__ out, int n)
{
    int i4 = (blockIdx.x * blockDim.x + threadIdx.x) * 4;
    if (i4 + 4 <= n) {
        float4 v = *reinterpret_cast<const float4*>(in + i4);
        ushort4 o = make_ushort4(f2b(v.x), f2b(v.y), f2b(v.z), f2b(v.w));
        *reinterpret_cast<ushort4*>(out + i4) = o;
    } else {
        for (; i4 < n; ++i4) out[i4] = f2b(in[i4]);
    }
}

// ======================== edge-index dtype handling ========================
__global__ void detect_kernel(const int* __restrict__ w, int nwords, int* flag)
{
    int i = blockIdx.x * blockDim.x + threadIdx.x;
    int odd = 2 * i + 1;
    if (odd < nwords && w[odd] != 0) atomicOr(flag, 1);
}

// decode edges + dst histogram in one pass
__global__ void convert_hist_kernel(const int* __restrict__ w, const int* __restrict__ flag,
                                    int* __restrict__ src, int* __restrict__ dst,
                                    int* __restrict__ deg, int E)
{
    int i = blockIdx.x * blockDim.x + threadIdx.x;
    if (i >= E) return;
    int s, d;
    if (*flag == 0) { s = w[2 * i]; d = w[2 * E + 2 * i]; }
    else            { s = w[i];     d = w[E + i]; }
    src[i] = s; dst[i] = d;
    atomicAdd(deg + d, 1);
}

// ======================== CSR build ========================
#define SCAN_T 1024
__global__ __launch_bounds__(SCAN_T) void scan_kernel(
    const int* __restrict__ deg, int* __restrict__ off, int n)
{
    __shared__ int part[SCAN_T];
    int t = threadIdx.x;
    int per = (n + SCAN_T - 1) / SCAN_T;
    int b0 = t * per, b1 = min(b0 + per, n);
    int s = 0;
    for (int i = b0; i < b1; ++i) s += deg[i];
    part[t] = s;
    __syncthreads();
    for (int d = 1; d < SCAN_T; d <<= 1) {
        int v = (t >= d) ? part[t - d] : 0;
        __syncthreads();
        part[t] += v;
        __syncthreads();
    }
    int run = (t == 0) ? 0 : part[t - 1];
    for (int i = b0; i < b1; ++i) { off[i] = run; run += deg[i]; }
    if (t == SCAN_T - 1) off[n] = run;
}

__global__ void scatter_kernel(const int* __restrict__ src, const int* __restrict__ dst,
                               const int* __restrict__ off, int* __restrict__ cnt,
                               int* __restrict__ srcs, int E)
{
    int i = blockIdx.x * blockDim.x + threadIdx.x;
    if (i >= E) return;
    int d = dst[i];
    int pos = off[d] + atomicAdd(cnt + d, 1);
    srcs[pos] = src[i];
}

// ======================== attention logits ========================
__global__ void al_bf16_kernel(const ushort_t* __restrict__ h,
                               const float* __restrict__ a_s, const float* __restrict__ a_d,
                               float* __restrict__ als, float* __restrict__ ald,
                               int Nn, int Hh, int Cc)
{
    int wid  = (blockIdx.x * blockDim.x + threadIdx.x) >> 6;
    int lane = threadIdx.x & 63;
    if (wid >= Nn * Hh) return;
    int n = wid / Hh, hh = wid - n * Hh;
    const ushort_t* hp = h + (size_t)n * Hh * Cc + hh * Cc;
    float s1 = 0.f, s2 = 0.f;
    int c = lane * 2;
    if (c < Cc) {
        unsigned w = *reinterpret_cast<const unsigned*>(hp + c);
        float f0 = b2f((ushort_t)(w & 0xffffu)), f1 = b2f((ushort_t)(w >> 16));
        float2 as2 = *reinterpret_cast<const float2*>(a_s + hh * Cc + c);
        float2 ad2 = *reinterpret_cast<const float2*>(a_d + hh * Cc + c);
        s1 = f0 * as2.x + f1 * as2.y;
        s2 = f0 * ad2.x + f1 * ad2.y;
    }
#pragma unroll
    for (int o = 32; o; o >>= 1) {
        s1 += __shfl_down(s1, o);
        s2 += __shfl_down(s2, o);
    }
    if (lane == 0) { als[wid] = s1; ald[wid] = s2; }
}

// fp32 input variant (layer 3, H=1, Cc=120)
__global__ void al_f32_kernel(const float* __restrict__ h,
                              const float* __restrict__ a_s, const float* __restrict__ a_d,
                              float* __restrict__ als, float* __restrict__ ald, int Nn)
{
    int wid  = (blockIdx.x * blockDim.x + threadIdx.x) >> 6;
    int lane = threadIdx.x & 63;
    if (wid >= Nn) return;
    const float* hp = h + (size_t)wid * CH;
    float s1 = 0.f, s2 = 0.f;
    int c = lane * 2;
    if (c < CH) {
        float2 hv  = *reinterpret_cast<const float2*>(hp + c);
        float2 as2 = *reinterpret_cast<const float2*>(a_s + c);
        float2 ad2 = *reinterpret_cast<const float2*>(a_d + c);
        s1 = hv.x * as2.x + hv.y * as2.y;
        s2 = hv.x * ad2.x + hv.y * ad2.y;
    }
#pragma unroll
    for (int o = 32; o; o >>= 1) {
        s1 += __shfl_down(s1, o);
        s2 += __shfl_down(s2, o);
    }
    if (lane == 0) { als[wid] = s1; ald[wid] = s2; }
}

// ======================== fused CSR segment softmax ========================
template<int HH, int LOGH>
__global__ void softmax_csr_kernel(const float* __restrict__ als,
                                   const float* __restrict__ ald,
                                   const int* __restrict__ off,
                                   const int* __restrict__ srcs,
                                   float* __restrict__ ebuf, int Nn)
{
    const int d = blockIdx.x * (blockDim.x >> 6) + (threadIdx.x >> 6);
    if (d >= Nn) return;
    const int lane = threadIdx.x & 63;
    const int h = lane & (HH - 1);
    const int j = lane >> LOGH;
    const int JS = 64 >> LOGH;
    const int start = off[d], end = off[d + 1];
    const float aldv = ald[d * HH + h];
    float m = -1e30f, ssum = 0.f;
    for (int base = start; base < end; base += JS) {
        int e = base + j;
        float v = -1e30f;
        if (e < end) {
            int s = srcs[e];
            float x = als[s * HH + h] + aldv;
            v = (x > 0.f) ? x : NEG_SLOPE * x;
            ebuf[(size_t)e * HH + h] = v;
        }
        float cm = v;
#pragma unroll
        for (int o = HH; o <= 32; o <<= 1) cm = fmaxf(cm, __shfl_xor(cm, o));
        float mnew = fmaxf(m, cm);
        float ex = (e < end) ? __expf(v - mnew) : 0.f;
#pragma unroll
        for (int o = HH; o <= 32; o <<= 1) ex += __shfl_xor(ex, o);
        ssum = ssum * __expf(m - mnew) + ex;
        m = mnew;
    }
    float rs = 1.f / ssum;
    for (int base = start; base < end; base += JS) {
        int e = base + j;
        if (e < end) {
            float v = ebuf[(size_t)e * HH + h];
            ebuf[(size_t)e * HH + h] = __expf(v - m) * rs;
        }
    }
}

// ======================== aggregation: block per node, no LDS/syncs ========================
template<int ACT>
__global__ __launch_bounds__(256) void agg_node_kernel(
    const ushort_t* __restrict__ h, const float* __restrict__ ebuf,
    const int* __restrict__ off, const int* __restrict__ srcs,
    const float* __restrict__ bias, ushort_t* __restrict__ outb)
{
    const int d = blockIdx.x;
    const int t = threadIdx.x;
    if (t >= 240) return;
    const int col = t * 8;
    const int head = col / CH;
    const int start = off[d], end = off[d + 1];
    float acc[8] = {0.f, 0.f, 0.f, 0.f, 0.f, 0.f, 0.f, 0.f};
    int e = start;
    for (; e + 2 <= end; e += 2) {
        int s0 = srcs[e], s1 = srcs[e + 1];
        float a0 = ebuf[(size_t)e * NH + head];
        float a1 = ebuf[(size_t)(e + 1) * NH + head];
        short8 v0 = *reinterpret_cast<const short8*>(h + (size_t)s0 * 1920 + col);
        short8 v1 = *reinterpret_cast<const short8*>(h + (size_t)s1 * 1920 + col);
#pragma unroll
        for (int k = 0; k < 8; ++k)
            acc[k] = fmaf(b2f((ushort_t)v1[k]), a1,
                          fmaf(b2f((ushort_t)v0[k]), a0, acc[k]));
    }
    if (e < end) {
        int s0 = srcs[e];
        float a0 = ebuf[(size_t)e * NH + head];
        short8 v0 = *reinterpret_cast<const short8*>(h + (size_t)s0 * 1920 + col);
#pragma unroll
        for (int k = 0; k < 8; ++k)
            acc[k] = fmaf(b2f((ushort_t)v0[k]), a0, acc[k]);
    }
    short8 o;
#pragma unroll
    for (int k = 0; k < 8; ++k) {
        float v = acc[k] + bias[col + k];
        if (ACT) v = (v > 0.f) ? v : expm1f(v);
        o[k] = (short)f2b(v);
    }
    *reinterpret_cast<short8*>(outb + (size_t)d * 1920 + col) = o;
}

// H=1 layer-3 variant: fp32 h input, 60 lanes x float2, bf16 out stride 128
__global__ __launch_bounds__(64) void agg_node1f_kernel(
    const float* __restrict__ h, const float* __restrict__ ebuf,
    const int* __restrict__ off, const int* __restrict__ srcs,
    const float* __restrict__ bias, ushort_t* __restrict__ outb)
{
    const int d = blockIdx.x;
    const int t = threadIdx.x;
    if (t >= 60) return;
    const int col = t * 2;
    const int start = off[d], end = off[d + 1];
    float acc0 = 0.f, acc1 = 0.f;
    for (int e = start; e < end; ++e) {
        int s = srcs[e];
        float a = ebuf[e];
        float2 w = *reinterpret_cast<const float2*>(h + (size_t)s * CH + col);
        acc0 = fmaf(w.x, a, acc0);
        acc1 = fmaf(w.y, a, acc1);
    }
    float v0 = acc0 + bias[col], v1 = acc1 + bias[col + 1];
    unsigned o = (unsigned)f2b(v0) | ((unsigned)f2b(v1) << 16);
    *reinterpret_cast<unsigned*>(outb + (size_t)d * 128 + col) = o;
}

// ======================== launch ========================
extern "C" void kernel_launch(void* const* d_in, const int* in_sizes, int n_in,
                              void* d_out, int out_size, void* d_ws, size_t ws_size,
                              hipStream_t stream)
{
    const float* x   = (const float*)d_in[0];
    const int*   ei  = (const int*)  d_in[1];
    const float* W1  = (const float*)d_in[2];
    const float* a1s = (const float*)d_in[3];
    const float* a1d = (const float*)d_in[4];
    const float* b1  = (const float*)d_in[5];
    const float* W2  = (const float*)d_in[6];
    const float* a2s = (const float*)d_in[7];
    const float* a2d = (const float*)d_in[8];
    const float* b2  = (const float*)d_in[9];
    const float* W3  = (const float*)d_in[10];
    const float* a3s = (const float*)d_in[11];
    const float* a3d = (const float*)d_in[12];
    const float* b3  = (const float*)d_in[13];
    const float* fcW = (const float*)d_in[14];
    const float* fcb = (const float*)d_in[15];

    float* out = (float*)d_out;
    const int N = N_NODES, E = N_EDGES;
    const int F16 = NH * CH;                 // 1920

    // ---- scratch inside d_out (FC overwrites all of d_out last)
    ushort_t* hraw  = (ushort_t*)out;                    // [MPAD][1920]
    ushort_t* hagg  = hraw + (size_t)MPAD * F16;         // [MPAD][1920]
    ushort_t* xb    = hagg + (size_t)MPAD * F16;         // [MPAD][128]
    ushort_t* W1t   = xb   + (size_t)MPAD * F_IN;        // [128][128+] -> [1920 rows? no: [F16? see prep]
    ushort_t* W2t   = W1t  + (size_t)F16 * F_IN;         // [1920][1920]
    ushort_t* W3t   = W2t  + (size_t)F16 * F16;          // [128][1920]
    float*    h3tmp = (float*)(W3t + (size_t)128 * F16); // [N][120] fp32 (split-K out)
    float*    als   = h3tmp + (size_t)N * CH;
    float*    ald   = als + (size_t)N * NH;
    float*    ebuf  = ald + (size_t)N * NH;              // [E][16] sorted alpha
    int*      srcv  = (int*)(ebuf + (size_t)E * NH);
    int*      dstv  = srcv + E;
    int*      srcs  = dstv + E;
    int*      flag  = srcs + E;
    int*      deg   = flag + 1;                          // [N]
    int*      offv  = deg + N;                           // [N+1]
    int*      cnt   = offv + N + 1;                      // [N]
    // ---- d_ws: FC inputs (read while FC writes d_out)
    ushort_t* h3bb = (ushort_t*)d_ws;                    // [MPAD][128]
    ushort_t* fcWt = h3bb + (size_t)MPAD * 128;          // [MPAD][128]

    // ---- all zeroing up front (flag..cnt are contiguous -> one memset)
    hipMemsetAsync(flag, 0, (size_t)(3 * N + 2) * 4, stream);
    hipMemsetAsync(h3tmp, 0, (size_t)N * CH * 4, stream);

    // ---- edge decode + CSR build
    detect_kernel      <<<(E + 255) / 256, 256, 0, stream>>>(ei, 2 * E, flag);
    convert_hist_kernel<<<(E + 255) / 256, 256, 0, stream>>>(ei, flag, srcv, dstv, deg, E);
    scan_kernel        <<<1, SCAN_T, 0, stream>>>(deg, offv, N);
    scatter_kernel     <<<(E + 255) / 256, 256, 0, stream>>>(srcv, dstv, offv, cnt, srcs, E);

    // ---- input/weight prep (merged)
    f2b_kernel<<<(N * F_IN / 4 + 255) / 256, 256, 0, stream>>>(x, xb, N * F_IN);
    prep4_kernel<<<5344, 256, 0, stream>>>(W1, W2, W3, fcW, W1t, W2t, W3t, fcWt);

    dim3 gBig(F16 / GBN, MPAD / GBM);        // (15,79)

    // =============== layer 1 ===============
    gemm_mfma_kernel<0, 1><<<gBig, 256, 0, stream>>>(xb, W1t, nullptr, hraw, N, F16, F_IN);
    al_bf16_kernel<<<(N * NH + 3) / 4, 256, 0, stream>>>(hraw, a1s, a1d, als, ald, N, NH, CH);
    softmax_csr_kernel<16, 4><<<(N + 3) / 4, 256, 0, stream>>>(als, ald, offv, srcs, ebuf, N);
    agg_node_kernel<1><<<N, 256, 0, stream>>>(hraw, ebuf, offv, srcs, b1, hagg);

    // =============== layer 2 ===============
    gemm_mfma_kernel<0, 1><<<gBig, 256, 0, stream>>>(hagg, W2t, nullptr, hraw, N, F16, F16);
    al_bf16_kernel<<<(N * NH + 3) / 4, 256, 0, stream>>>(hraw, a2s, a2d, als, ald, N, NH, CH);
    softmax_csr_kernel<16, 4><<<(N + 3) / 4, 256, 0, stream>>>(als, ald, offv, srcs, ebuf, N);
    agg_node_kernel<1><<<N, 256, 0, stream>>>(hraw, ebuf, offv, srcs, b2, hagg);

    // =============== layer 3 (H=1), split-K GEMM, fp32 chain ===============
    dim3 gL3(1, MPAD / GBM, 6);              // K split 1920 -> 6 x 320
    gemm_splitk_kernel<<<gL3, 256, 0, stream>>>(hagg, W3t, h3tmp, N, CH, F16, 320);
    al_f32_kernel<<<(N + 3) / 4, 256, 0, stream>>>(h3tmp, a3s, a3d, als, ald, N);
    softmax_csr_kernel<1, 0><<<(N + 3) / 4, 256, 0, stream>>>(als, ald, offv, srcs, ebuf, N);
    agg_node1f_kernel<<<N, 64, 0, stream>>>(h3tmp, ebuf, offv, srcs, b3, h3bb);

    // =============== FC + ReLU (coalesced epilogue) ===============
    dim3 gFC(MPAD / GBN, MPAD / GBM);        // (79,79); guards trim to 10000
    gemm_fc_kernel<<<gFC, 256, 0, stream>>>(h3bb, fcWt, fcb, out, N, N, 128);
}

// Round 8
// 578.034 us; speedup vs baseline: 1.2130x; 1.0709x over previous
//
#include <hip/hip_runtime.h>
#include <hip/hip_bf16.h>
#include <math.h>

#define N_NODES 10000
#define N_EDGES 100000
#define F_IN    128
#define CH      120
#define NH      16
#define NEG_SLOPE 0.2f
#define MPAD    10112          // N padded to multiple of 128

typedef unsigned short ushort_t;
typedef short short8 __attribute__((ext_vector_type(8)));
typedef float floatx4 __attribute__((ext_vector_type(4)));

__device__ inline ushort_t f2b(float f) {            // fp32->bf16 RNE
    unsigned u = __float_as_uint(f);
    unsigned r = (u + 0x7fffu + ((u >> 16) & 1u)) >> 16;
    return (ushort_t)r;
}
__device__ inline float b2f(ushort_t u) { return __uint_as_float(((unsigned)u) << 16); }

// async global->LDS, 16B per lane (dest = wave-uniform base + lane*16)
__device__ __forceinline__ void gload16(const ushort_t* g, ushort_t* l) {
    __builtin_amdgcn_global_load_lds(
        (const __attribute__((address_space(1))) unsigned int*)g,
        (__attribute__((address_space(3))) unsigned int*)l,
        16, 0, 0);
}

// ======================== bf16 MFMA GEMM (m97 structure) ========================
#define GBM 128
#define GBN 128
#define GBK 32

template<int ACT, int OUTBF>
__global__ __launch_bounds__(256) void gemm_mfma_kernel(
    const ushort_t* __restrict__ A, const ushort_t* __restrict__ Bt,
    const float* __restrict__ bias, void* __restrict__ Cv,
    int M, int Nn, int K)
{
    __shared__ ushort_t As[GBM * GBK];
    __shared__ ushort_t Bs[GBN * GBK];
    const int t = threadIdx.x;
    const int lane = t & 63;
    const int wid = t >> 6;
    const int wr = wid >> 1, wc = wid & 1;
    const int row0 = blockIdx.y * GBM, col0 = blockIdx.x * GBN;
    const int laneRow = lane & 15;
    const int laneK   = (lane >> 4) * 8;
    const int srow = lane >> 2;
    const int skq  = (lane & 3) * 8;

    floatx4 acc[4][4];
#pragma unroll
    for (int m = 0; m < 4; ++m)
#pragma unroll
        for (int n = 0; n < 4; ++n)
            acc[m][n] = (floatx4){0.f, 0.f, 0.f, 0.f};

    for (int k0 = 0; k0 < K; k0 += GBK) {
#pragma unroll
        for (int i = 0; i < 2; ++i) {
            int ai = wid * 2 + i;
            gload16(A + (size_t)(row0 + ai * 16 + srow) * K + k0 + skq,
                    &As[ai * 512]);
        }
#pragma unroll
        for (int i = 0; i < 2; ++i) {
            int bi = wid * 2 + i;
            gload16(Bt + (size_t)(col0 + bi * 16 + srow) * K + k0 + skq,
                    &Bs[bi * 512]);
        }
        __syncthreads();

        short8 af[4], bf[4];
#pragma unroll
        for (int m = 0; m < 4; ++m)
            af[m] = *reinterpret_cast<const short8*>(
                &As[(wr * 64 + m * 16 + laneRow) * GBK + laneK]);
#pragma unroll
        for (int n = 0; n < 4; ++n)
            bf[n] = *reinterpret_cast<const short8*>(
                &Bs[(wc * 64 + n * 16 + laneRow) * GBK + laneK]);
#pragma unroll
        for (int m = 0; m < 4; ++m)
#pragma unroll
            for (int n = 0; n < 4; ++n)
                acc[m][n] = __builtin_amdgcn_mfma_f32_16x16x32_bf16(
                    af[m], bf[n], acc[m][n], 0, 0, 0);
        __syncthreads();
    }

    const int orow = (lane >> 4) * 4;
#pragma unroll
    for (int m = 0; m < 4; ++m) {
#pragma unroll
        for (int n = 0; n < 4; ++n) {
            int gc = col0 + wc * 64 + n * 16 + laneRow;
            if (gc >= Nn) continue;
            float bv = bias ? bias[gc] : 0.f;
#pragma unroll
            for (int j = 0; j < 4; ++j) {
                int gr = row0 + wr * 64 + m * 16 + orow + j;
                if (gr >= M) continue;
                float v = acc[m][n][j] + bv;
                if (ACT == 1) v = fmaxf(v, 0.f);
                if (OUTBF) ((ushort_t*)Cv)[(size_t)gr * Nn + gc] = f2b(v);
                else       ((float*)Cv)   [(size_t)gr * Nn + gc] = v;
            }
        }
    }
}

// ---- split-K variant: fp32 atomicAdd into C (C pre-zeroed)
__global__ __launch_bounds__(256) void gemm_splitk_kernel(
    const ushort_t* __restrict__ A, const ushort_t* __restrict__ Bt,
    float* __restrict__ C, int M, int Nn, int K, int KS)
{
    __shared__ ushort_t As[GBM * GBK];
    __shared__ ushort_t Bs[GBN * GBK];
    const int t = threadIdx.x;
    const int lane = t & 63;
    const int wid = t >> 6;
    const int wr = wid >> 1, wc = wid & 1;
    const int row0 = blockIdx.y * GBM, col0 = blockIdx.x * GBN;
    const int kbeg = blockIdx.z * KS, kend = kbeg + KS;
    const int laneRow = lane & 15;
    const int laneK   = (lane >> 4) * 8;
    const int srow = lane >> 2;
    const int skq  = (lane & 3) * 8;

    floatx4 acc[4][4];
#pragma unroll
    for (int m = 0; m < 4; ++m)
#pragma unroll
        for (int n = 0; n < 4; ++n)
            acc[m][n] = (floatx4){0.f, 0.f, 0.f, 0.f};

    for (int k0 = kbeg; k0 < kend; k0 += GBK) {
#pragma unroll
        for (int i = 0; i < 2; ++i) {
            int ai = wid * 2 + i;
            gload16(A + (size_t)(row0 + ai * 16 + srow) * K + k0 + skq,
                    &As[ai * 512]);
        }
#pragma unroll
        for (int i = 0; i < 2; ++i) {
            int bi = wid * 2 + i;
            gload16(Bt + (size_t)(col0 + bi * 16 + srow) * K + k0 + skq,
                    &Bs[bi * 512]);
        }
        __syncthreads();

        short8 af[4], bf[4];
#pragma unroll
        for (int m = 0; m < 4; ++m)
            af[m] = *reinterpret_cast<const short8*>(
                &As[(wr * 64 + m * 16 + laneRow) * GBK + laneK]);
#pragma unroll
        for (int n = 0; n < 4; ++n)
            bf[n] = *reinterpret_cast<const short8*>(
                &Bs[(wc * 64 + n * 16 + laneRow) * GBK + laneK]);
#pragma unroll
        for (int m = 0; m < 4; ++m)
#pragma unroll
            for (int n = 0; n < 4; ++n)
                acc[m][n] = __builtin_amdgcn_mfma_f32_16x16x32_bf16(
                    af[m], bf[n], acc[m][n], 0, 0, 0);
        __syncthreads();
    }

    const int orow = (lane >> 4) * 4;
#pragma unroll
    for (int m = 0; m < 4; ++m) {
#pragma unroll
        for (int n = 0; n < 4; ++n) {
            int gc = col0 + wc * 64 + n * 16 + laneRow;
            if (gc >= Nn) continue;
#pragma unroll
            for (int j = 0; j < 4; ++j) {
                int gr = row0 + wr * 64 + m * 16 + orow + j;
                if (gr >= M) continue;
                atomicAdd(&C[(size_t)gr * Nn + gc], acc[m][n][j]);
            }
        }
    }
}

// ---- FC kernel: bias+ReLU fused, LDS-staged coalesced float4 C-writes
__global__ __launch_bounds__(256) void gemm_fc_kernel(
    const ushort_t* __restrict__ A, const ushort_t* __restrict__ Bt,
    const float* __restrict__ bias, float* __restrict__ C,
    int M, int Nn, int K)
{
    __shared__ ushort_t As[GBM * GBK];
    __shared__ ushort_t Bs[GBN * GBK];
    __shared__ float ct[32][132];
    const int t = threadIdx.x;
    const int lane = t & 63;
    const int wid = t >> 6;
    const int wr = wid >> 1, wc = wid & 1;
    const int row0 = blockIdx.y * GBM, col0 = blockIdx.x * GBN;
    const int laneRow = lane & 15;
    const int laneK   = (lane >> 4) * 8;
    const int srow = lane >> 2;
    const int skq  = (lane & 3) * 8;

    floatx4 acc[4][4];
#pragma unroll
    for (int m = 0; m < 4; ++m)
#pragma unroll
        for (int n = 0; n < 4; ++n)
            acc[m][n] = (floatx4){0.f, 0.f, 0.f, 0.f};

    for (int k0 = 0; k0 < K; k0 += GBK) {
#pragma unroll
        for (int i = 0; i < 2; ++i) {
            int ai = wid * 2 + i;
            gload16(A + (size_t)(row0 + ai * 16 + srow) * K + k0 + skq,
                    &As[ai * 512]);
        }
#pragma unroll
        for (int i = 0; i < 2; ++i) {
            int bi = wid * 2 + i;
            gload16(Bt + (size_t)(col0 + bi * 16 + srow) * K + k0 + skq,
                    &Bs[bi * 512]);
        }
        __syncthreads();

        short8 af[4], bf[4];
#pragma unroll
        for (int m = 0; m < 4; ++m)
            af[m] = *reinterpret_cast<const short8*>(
                &As[(wr * 64 + m * 16 + laneRow) * GBK + laneK]);
#pragma unroll
        for (int n = 0; n < 4; ++n)
            bf[n] = *reinterpret_cast<const short8*>(
                &Bs[(wc * 64 + n * 16 + laneRow) * GBK + laneK]);
#pragma unroll
        for (int m = 0; m < 4; ++m)
#pragma unroll
            for (int n = 0; n < 4; ++n)
                acc[m][n] = __builtin_amdgcn_mfma_f32_16x16x32_bf16(
                    af[m], bf[n], acc[m][n], 0, 0, 0);
        __syncthreads();
    }

    const int orow = (lane >> 4) * 4;
#pragma unroll
    for (int m = 0; m < 4; ++m) {
        __syncthreads();
#pragma unroll
        for (int n = 0; n < 4; ++n)
#pragma unroll
            for (int j = 0; j < 4; ++j)
                ct[wr * 16 + orow + j][wc * 64 + n * 16 + laneRow] = acc[m][n][j];
        __syncthreads();
#pragma unroll
        for (int i = 0; i < 4; ++i) {
            int idx = t + i * 256;
            int lr = idx >> 5, lc = (idx & 31) * 4;
            int gr = row0 + (lr & 15) + m * 16 + (lr >> 4) * 64;
            if (gr >= M) continue;
            int gc = col0 + lc;
            float4 v = *reinterpret_cast<const float4*>(&ct[lr][lc]);
            if (gc + 4 <= Nn) {
                float4 b4 = *reinterpret_cast<const float4*>(bias + gc);
                v.x = fmaxf(v.x + b4.x, 0.f);
                v.y = fmaxf(v.y + b4.y, 0.f);
                v.z = fmaxf(v.z + b4.z, 0.f);
                v.w = fmaxf(v.w + b4.w, 0.f);
                *reinterpret_cast<float4*>(C + (size_t)gr * Nn + gc) = v;
            } else {
                float vv[4] = {v.x, v.y, v.z, v.w};
#pragma unroll
                for (int q = 0; q < 4; ++q)
                    if (gc + q < Nn)
                        C[(size_t)gr * Nn + gc + q] = fmaxf(vv[q] + bias[gc + q], 0.f);
            }
        }
    }
}

// ======================== merged prep: x convert + 4 weight transposes ========================
__global__ __launch_bounds__(256) void prep5_kernel(
    const float* __restrict__ x, const float* __restrict__ W1,
    const float* __restrict__ W2, const float* __restrict__ W3,
    const float* __restrict__ fcW,
    ushort_t* __restrict__ xb, ushort_t* __restrict__ W1t,
    ushort_t* __restrict__ W2t, ushort_t* __restrict__ W3t,
    ushort_t* __restrict__ fcWt)
{
    int b = blockIdx.x;
    if (b < 1250) {                      // x copy-convert: 1250 * 1024 = N*F_IN
        int i0 = b * 1024 + threadIdx.x * 4;
        float4 v = *reinterpret_cast<const float4*>(x + i0);
        ushort4 o = make_ushort4(f2b(v.x), f2b(v.y), f2b(v.z), f2b(v.w));
        *reinterpret_cast<ushort4*>(xb + i0) = o;
        return;
    }
    b -= 1250;
    const float* in; ushort_t* outp; int R, Cc, Kpad, tilesK;
    if (b < 240)       { in = W1;  outp = W1t;  R = 128;  Cc = 1920;  Kpad = 128;  tilesK = 4; }
    else if (b < 3840) { b -= 240;  in = W2;  outp = W2t;  R = 1920; Cc = 1920;  Kpad = 1920; tilesK = 60; }
    else if (b < 4080) { b -= 3840; in = W3;  outp = W3t;  R = 1920; Cc = 120;   Kpad = 1920; tilesK = 60; }
    else               { b -= 4080; in = fcW; outp = fcWt; R = 120;  Cc = 10000; Kpad = 128;  tilesK = 4; }
    const int k0 = (b % tilesK) * 32, n0 = (b / tilesK) * 32;
    __shared__ float tile[32][33];
    const int tx = threadIdx.x & 31, ty = threadIdx.x >> 5;
#pragma unroll
    for (int i = 0; i < 4; ++i) {
        int r = k0 + ty + i * 8, c = n0 + tx;
        tile[ty + i * 8][tx] = (r < R && c < Cc) ? in[(size_t)r * Cc + c] : 0.f;
    }
    __syncthreads();
#pragma unroll
    for (int i = 0; i < 4; ++i) {
        int orow = n0 + ty + i * 8, ocol = k0 + tx;
        outp[(size_t)orow * Kpad + ocol] = f2b(tile[tx][ty + i * 8]);
    }
}

// ======================== edge-index dtype handling ========================
__global__ void detect_kernel(const int* __restrict__ w, int nwords, int* flag)
{
    int i = blockIdx.x * blockDim.x + threadIdx.x;
    int odd = 2 * i + 1;
    if (odd < nwords && w[odd] != 0) atomicOr(flag, 1);
}

__global__ void convert_hist_kernel(const int* __restrict__ w, const int* __restrict__ flag,
                                    int* __restrict__ src, int* __restrict__ dst,
                                    int* __restrict__ deg, int E)
{
    int i = blockIdx.x * blockDim.x + threadIdx.x;
    if (i >= E) return;
    int s, d;
    if (*flag == 0) { s = w[2 * i]; d = w[2 * E + 2 * i]; }
    else            { s = w[i];     d = w[E + i]; }
    src[i] = s; dst[i] = d;
    atomicAdd(deg + d, 1);
}

// ======================== CSR build ========================
#define SCAN_T 1024
__global__ __launch_bounds__(SCAN_T) void scan_kernel(
    const int* __restrict__ deg, int* __restrict__ off, int n)
{
    __shared__ int part[SCAN_T];
    int t = threadIdx.x;
    int per = (n + SCAN_T - 1) / SCAN_T;
    int b0 = t * per, b1 = min(b0 + per, n);
    int s = 0;
    for (int i = b0; i < b1; ++i) s += deg[i];
    part[t] = s;
    __syncthreads();
    for (int d = 1; d < SCAN_T; d <<= 1) {
        int v = (t >= d) ? part[t - d] : 0;
        __syncthreads();
        part[t] += v;
        __syncthreads();
    }
    int run = (t == 0) ? 0 : part[t - 1];
    for (int i = b0; i < b1; ++i) { off[i] = run; run += deg[i]; }
    if (t == SCAN_T - 1) off[n] = run;
}

__global__ void scatter_kernel(const int* __restrict__ src, const int* __restrict__ dst,
                               const int* __restrict__ off, int* __restrict__ cnt,
                               int* __restrict__ srcs, int E)
{
    int i = blockIdx.x * blockDim.x + threadIdx.x;
    if (i >= E) return;
    int d = dst[i];
    int pos = off[d] + atomicAdd(cnt + d, 1);
    srcs[pos] = src[i];
}

// ======================== attention logits: one block per node (H=16) ========================
__global__ __launch_bounds__(256) void al_node_kernel(
    const ushort_t* __restrict__ h,
    const float* __restrict__ a_s, const float* __restrict__ a_d,
    float* __restrict__ als, float* __restrict__ ald)
{
    const int n = blockIdx.x;
    const int t = threadIdx.x;
    __shared__ float ps[240], pd[240];
    if (t < 240) {
        const int col = t * 8;
        short8 v = *reinterpret_cast<const short8*>(h + (size_t)n * 1920 + col);
        float4 s0 = *reinterpret_cast<const float4*>(a_s + col);
        float4 s1 = *reinterpret_cast<const float4*>(a_s + col + 4);
        float4 d0 = *reinterpret_cast<const float4*>(a_d + col);
        float4 d1 = *reinterpret_cast<const float4*>(a_d + col + 4);
        float f[8];
#pragma unroll
        for (int k = 0; k < 8; ++k) f[k] = b2f((ushort_t)v[k]);
        float x1 = f[0]*s0.x + f[1]*s0.y + f[2]*s0.z + f[3]*s0.w
                 + f[4]*s1.x + f[5]*s1.y + f[6]*s1.z + f[7]*s1.w;
        float x2 = f[0]*d0.x + f[1]*d0.y + f[2]*d0.z + f[3]*d0.w
                 + f[4]*d1.x + f[5]*d1.y + f[6]*d1.z + f[7]*d1.w;
        ps[t] = x1; pd[t] = x2;
    }
    __syncthreads();
    if (t < 16) {
        float s1 = 0.f, s2 = 0.f;
#pragma unroll
        for (int j = 0; j < 15; ++j) {
            s1 += ps[t * 15 + j];
            s2 += pd[t * 15 + j];
        }
        als[n * 16 + t] = s1;
        ald[n * 16 + t] = s2;
    }
}

// fp32 input variant (layer 3, H=1, Cc=120)
__global__ void al_f32_kernel(const float* __restrict__ h,
                              const float* __restrict__ a_s, const float* __restrict__ a_d,
                              float* __restrict__ als, float* __restrict__ ald, int Nn)
{
    int wid  = (blockIdx.x * blockDim.x + threadIdx.x) >> 6;
    int lane = threadIdx.x & 63;
    if (wid >= Nn) return;
    const float* hp = h + (size_t)wid * CH;
    float s1 = 0.f, s2 = 0.f;
    int c = lane * 2;
    if (c < CH) {
        float2 hv  = *reinterpret_cast<const float2*>(hp + c);
        float2 as2 = *reinterpret_cast<const float2*>(a_s + c);
        float2 ad2 = *reinterpret_cast<const float2*>(a_d + c);
        s1 = hv.x * as2.x + hv.y * as2.y;
        s2 = hv.x * ad2.x + hv.y * ad2.y;
    }
#pragma unroll
    for (int o = 32; o; o >>= 1) {
        s1 += __shfl_down(s1, o);
        s2 += __shfl_down(s2, o);
    }
    if (lane == 0) { als[wid] = s1; ald[wid] = s2; }
}

// ======================== fused online softmax + aggregation (H=16) ========================
// One block per dst node. Flash-style: running (m, S) per head, chunked edges.
#define SCHUNK 32
template<int ACT>
__global__ __launch_bounds__(256) void sagg_kernel(
    const ushort_t* __restrict__ h,
    const float* __restrict__ als, const float* __restrict__ ald,
    const int* __restrict__ off, const int* __restrict__ srcs,
    const float* __restrict__ bias, ushort_t* __restrict__ outb)
{
    const int d = blockIdx.x;
    const int t = threadIdx.x;
    const int start = off[d], end = off[d + 1];
    __shared__ float lAl[SCHUNK][NH];     // chunk logits -> unnormalized exp
    __shared__ int   lSrc[SCHUNK];
    __shared__ float lM[NH], lS[NH], lScale[NH], lAld[NH];
    const int col = t * 8;                // t < 240 active for accumulation
    const int head = (t < 240) ? (col / CH) : 0;
    float acc[8] = {0.f, 0.f, 0.f, 0.f, 0.f, 0.f, 0.f, 0.f};
    if (t < NH) { lM[t] = -1e30f; lS[t] = 0.f; lAld[t] = ald[d * NH + t]; }
    __syncthreads();

    for (int base = start; base < end; base += SCHUNK) {
        const int nb = min(SCHUNK, end - base);
        if (t < nb) lSrc[t] = srcs[base + t];
        for (int it = t; it < nb * NH; it += 256) {
            int j = it >> 4, hh = it & 15;
            int s = srcs[base + j];
            float xx = als[s * NH + hh] + lAld[hh];
            lAl[j][hh] = (xx > 0.f) ? xx : NEG_SLOPE * xx;
        }
        __syncthreads();                  // logits + lSrc ready
        if (t < NH) {
            float mc = -1e30f;
            for (int j = 0; j < nb; ++j) mc = fmaxf(mc, lAl[j][t]);
            float mnew = fmaxf(lM[t], mc);
            float sc = __expf(lM[t] - mnew);
            float s_c = 0.f;
            for (int j = 0; j < nb; ++j) {
                float e = __expf(lAl[j][t] - mnew);
                lAl[j][t] = e;
                s_c += e;
            }
            lS[t] = lS[t] * sc + s_c;
            lM[t] = mnew;
            lScale[t] = sc;
        }
        __syncthreads();                  // alphas + scale ready
        if (t < 240) {
            float sc = lScale[head];
#pragma unroll
            for (int k = 0; k < 8; ++k) acc[k] *= sc;
            int j = 0;
            for (; j + 2 <= nb; j += 2) {
                int s0 = lSrc[j], s1 = lSrc[j + 1];
                float a0 = lAl[j][head], a1 = lAl[j + 1][head];
                short8 v0 = *reinterpret_cast<const short8*>(h + (size_t)s0 * 1920 + col);
                short8 v1 = *reinterpret_cast<const short8*>(h + (size_t)s1 * 1920 + col);
#pragma unroll
                for (int k = 0; k < 8; ++k)
                    acc[k] = fmaf(b2f((ushort_t)v1[k]), a1,
                                  fmaf(b2f((ushort_t)v0[k]), a0, acc[k]));
            }
            if (j < nb) {
                int s0 = lSrc[j];
                float a0 = lAl[j][head];
                short8 v0 = *reinterpret_cast<const short8*>(h + (size_t)s0 * 1920 + col);
#pragma unroll
                for (int k = 0; k < 8; ++k)
                    acc[k] = fmaf(b2f((ushort_t)v0[k]), a0, acc[k]);
            }
        }
        __syncthreads();                  // done reading lAl/lSrc
    }

    if (t < 240) {
        float rs = 1.f / lS[head];
        short8 o;
#pragma unroll
        for (int k = 0; k < 8; ++k) {
            float v = acc[k] * rs + bias[col + k];
            if (ACT) v = (v > 0.f) ? v : expm1f(v);
            o[k] = (short)f2b(v);
        }
        *reinterpret_cast<short8*>(outb + (size_t)d * 1920 + col) = o;
    }
}

// H=1 fused variant: fp32 h [N][120], one 64-thread wave per node, bf16 out stride 128
__global__ __launch_bounds__(64) void sagg1_kernel(
    const float* __restrict__ h,
    const float* __restrict__ als, const float* __restrict__ ald,
    const int* __restrict__ off, const int* __restrict__ srcs,
    const float* __restrict__ bias, ushort_t* __restrict__ outb)
{
    const int d = blockIdx.x;
    const int t = threadIdx.x;
    const int start = off[d], end = off[d + 1];
    __shared__ float lA[64];
    __shared__ int   lSr[64];
    const float aldv = ald[d];
    float m = -1e30f, ssum = 0.f;
    float acc0 = 0.f, acc1 = 0.f;
    const int col = t * 2;                // t < 60 active

    for (int base = start; base < end; base += 64) {
        const int nb = min(64, end - base);
        float v = -1e30f;
        if (t < nb) {
            int s = srcs[base + t];
            lSr[t] = s;
            float xx = als[s] + aldv;
            v = (xx > 0.f) ? xx : NEG_SLOPE * xx;
        }
        float cm = v;
#pragma unroll
        for (int o = 32; o; o >>= 1) cm = fmaxf(cm, __shfl_xor(cm, o));
        float mnew = fmaxf(m, cm);
        float sc = __expf(m - mnew);
        float e = (t < nb) ? __expf(v - mnew) : 0.f;
        float es = e;
#pragma unroll
        for (int o = 32; o; o >>= 1) es += __shfl_xor(es, o);
        ssum = ssum * sc + es;
        m = mnew;
        lA[t] = e;
        __syncthreads();
        if (t < 60) {
            acc0 *= sc; acc1 *= sc;
            for (int j = 0; j < nb; ++j) {
                float a = lA[j];
                float2 w = *reinterpret_cast<const float2*>(h + (size_t)lSr[j] * CH + col);
                acc0 = fmaf(w.x, a, acc0);
                acc1 = fmaf(w.y, a, acc1);
            }
        }
        __syncthreads();
    }
    if (t < 60) {
        float rs = 1.f / ssum;
        float v0 = acc0 * rs + bias[col], v1 = acc1 * rs + bias[col + 1];
        unsigned o = (unsigned)f2b(v0) | ((unsigned)f2b(v1) << 16);
        *reinterpret_cast<unsigned*>(outb + (size_t)d * 128 + col) = o;
    }
}

// ======================== launch ========================
extern "C" void kernel_launch(void* const* d_in, const int* in_sizes, int n_in,
                              void* d_out, int out_size, void* d_ws, size_t ws_size,
                              hipStream_t stream)
{
    const float* x   = (const float*)d_in[0];
    const int*   ei  = (const int*)  d_in[1];
    const float* W1  = (const float*)d_in[2];
    const float* a1s = (const float*)d_in[3];
    const float* a1d = (const float*)d_in[4];
    const float* b1  = (const float*)d_in[5];
    const float* W2  = (const float*)d_in[6];
    const float* a2s = (const float*)d_in[7];
    const float* a2d = (const float*)d_in[8];
    const float* b2  = (const float*)d_in[9];
    const float* W3  = (const float*)d_in[10];
    const float* a3s = (const float*)d_in[11];
    const float* a3d = (const float*)d_in[12];
    const float* b3  = (const float*)d_in[13];
    const float* fcW = (const float*)d_in[14];
    const float* fcb = (const float*)d_in[15];

    float* out = (float*)d_out;
    const int N = N_NODES, E = N_EDGES;
    const int F16 = NH * CH;                 // 1920

    // ---- scratch inside d_out (FC overwrites all of d_out last)
    ushort_t* hraw  = (ushort_t*)out;                    // [MPAD][1920]
    ushort_t* hagg  = hraw + (size_t)MPAD * F16;         // [MPAD][1920]
    ushort_t* xb    = hagg + (size_t)MPAD * F16;         // [MPAD][128]
    ushort_t* W1t   = xb   + (size_t)MPAD * F_IN;        // [1920][128]
    ushort_t* W2t   = W1t  + (size_t)F16 * F_IN;         // [1920][1920]
    ushort_t* W3t   = W2t  + (size_t)F16 * F16;          // [128][1920]
    float*    h3tmp = (float*)(W3t + (size_t)128 * F16); // [N][120] fp32 (split-K out)
    float*    als   = h3tmp + (size_t)N * CH;
    float*    ald   = als + (size_t)N * NH;
    int*      srcv  = (int*)(ald + (size_t)N * NH);
    int*      dstv  = srcv + E;
    int*      srcs  = dstv + E;
    int*      flag  = srcs + E;
    int*      deg   = flag + 1;                          // [N]
    int*      offv  = deg + N;                           // [N+1]
    int*      cnt   = offv + N + 1;                      // [N]
    // ---- d_ws: FC inputs (read while FC writes d_out)
    ushort_t* h3bb = (ushort_t*)d_ws;                    // [MPAD][128]
    ushort_t* fcWt = h3bb + (size_t)MPAD * 128;          // [MPAD][128]

    // ---- zeroing up front (flag..cnt contiguous -> one memset)
    hipMemsetAsync(flag, 0, (size_t)(3 * N + 2) * 4, stream);
    hipMemsetAsync(h3tmp, 0, (size_t)N * CH * 4, stream);

    // ---- edge decode + CSR build
    detect_kernel      <<<(E + 255) / 256, 256, 0, stream>>>(ei, 2 * E, flag);
    convert_hist_kernel<<<(E + 255) / 256, 256, 0, stream>>>(ei, flag, srcv, dstv, deg, E);
    scan_kernel        <<<1, SCAN_T, 0, stream>>>(deg, offv, N);
    scatter_kernel     <<<(E + 255) / 256, 256, 0, stream>>>(srcv, dstv, offv, cnt, srcs, E);

    // ---- merged prep (x convert + 4 transposes)
    prep5_kernel<<<6594, 256, 0, stream>>>(x, W1, W2, W3, fcW, xb, W1t, W2t, W3t, fcWt);

    dim3 gBig(F16 / GBN, MPAD / GBM);        // (15,79)

    // =============== layer 1 ===============
    gemm_mfma_kernel<0, 1><<<gBig, 256, 0, stream>>>(xb, W1t, nullptr, hraw, N, F16, F_IN);
    al_node_kernel<<<N, 256, 0, stream>>>(hraw, a1s, a1d, als, ald);
    sagg_kernel<1><<<N, 256, 0, stream>>>(hraw, als, ald, offv, srcs, b1, hagg);

    // =============== layer 2 ===============
    gemm_mfma_kernel<0, 1><<<gBig, 256, 0, stream>>>(hagg, W2t, nullptr, hraw, N, F16, F16);
    al_node_kernel<<<N, 256, 0, stream>>>(hraw, a2s, a2d, als, ald);
    sagg_kernel<1><<<N, 256, 0, stream>>>(hraw, als, ald, offv, srcs, b2, hagg);

    // =============== layer 3 (H=1), split-K GEMM, fp32 chain ===============
    dim3 gL3(1, MPAD / GBM, 6);              // K split 1920 -> 6 x 320
    gemm_splitk_kernel<<<gL3, 256, 0, stream>>>(hagg, W3t, h3tmp, N, CH, F16, 320);
    al_f32_kernel<<<(N + 3) / 4, 256, 0, stream>>>(h3tmp, a3s, a3d, als, ald, N);
    sagg1_kernel<<<N, 64, 0, stream>>>(h3tmp, als, ald, offv, srcs, b3, h3bb);

    // =============== FC + ReLU (coalesced epilogue) ===============
    dim3 gFC(MPAD / GBN, MPAD / GBM);        // (79,79); guards trim to 10000
    gemm_fc_kernel<<<gFC, 256, 0, stream>>>(h3bb, fcWt, fcb, out, N, N, 128);
}

// Round 10
// 547.794 us; speedup vs baseline: 1.2800x; 1.0552x over previous
//
#include <hip/hip_runtime.h>
#include <hip/hip_bf16.h>
#include <math.h>

#define N_NODES 10000
#define N_EDGES 100000
#define F_IN    128
#define CH      120
#define NH      16
#define NEG_SLOPE 0.2f
#define MPAD    10112          // N padded to multiple of 128

typedef unsigned short ushort_t;
typedef short short8 __attribute__((ext_vector_type(8)));
typedef float floatx4 __attribute__((ext_vector_type(4)));

__device__ inline ushort_t f2b(float f) {            // fp32->bf16 RNE
    unsigned u = __float_as_uint(f);
    unsigned r = (u + 0x7fffu + ((u >> 16) & 1u)) >> 16;
    return (ushort_t)r;
}
__device__ inline float b2f(ushort_t u) { return __uint_as_float(((unsigned)u) << 16); }

// async global->LDS, 16B per lane (dest = wave-uniform base + lane*16)
__device__ __forceinline__ void gload16(const ushort_t* g, ushort_t* l) {
    __builtin_amdgcn_global_load_lds(
        (const __attribute__((address_space(1))) unsigned int*)g,
        (__attribute__((address_space(3))) unsigned int*)l,
        16, 0, 0);
}

// bijective XCD swizzle (m204)
__device__ __forceinline__ void xcd_swizzle(int& bx, int& by) {
    int gx = gridDim.x;
    int nwg = gx * gridDim.y;
    int lin = by * gx + bx;
    int q = nwg >> 3, r = nwg & 7;
    int xcd = lin & 7, idx = lin >> 3;
    int swz = (xcd < r) ? (xcd * (q + 1) + idx)
                        : (r * (q + 1) + (xcd - r) * q + idx);
    bx = swz % gx;
    by = swz / gx;
}

// ======================== bf16 MFMA GEMM (m97 structure) ========================
#define GBM 128
#define GBN 128
#define GBK 32

template<int ACT, int OUTBF>
__global__ __launch_bounds__(256) void gemm_mfma_kernel(
    const ushort_t* __restrict__ A, const ushort_t* __restrict__ Bt,
    const float* __restrict__ bias, void* __restrict__ Cv,
    int M, int Nn, int K)
{
    __shared__ ushort_t As[GBM * GBK];
    __shared__ ushort_t Bs[GBN * GBK];
    const int t = threadIdx.x;
    const int lane = t & 63;
    const int wid = t >> 6;
    const int wr = wid >> 1, wc = wid & 1;
    int bx = blockIdx.x, by = blockIdx.y;
    xcd_swizzle(bx, by);
    const int row0 = by * GBM, col0 = bx * GBN;
    const int laneRow = lane & 15;
    const int laneK   = (lane >> 4) * 8;
    const int srow = lane >> 2;
    const int skq  = (lane & 3) * 8;

    floatx4 acc[4][4];
#pragma unroll
    for (int m = 0; m < 4; ++m)
#pragma unroll
        for (int n = 0; n < 4; ++n)
            acc[m][n] = (floatx4){0.f, 0.f, 0.f, 0.f};

    for (int k0 = 0; k0 < K; k0 += GBK) {
#pragma unroll
        for (int i = 0; i < 2; ++i) {
            int ai = wid * 2 + i;
            gload16(A + (size_t)(row0 + ai * 16 + srow) * K + k0 + skq,
                    &As[ai * 512]);
        }
#pragma unroll
        for (int i = 0; i < 2; ++i) {
            int bi = wid * 2 + i;
            gload16(Bt + (size_t)(col0 + bi * 16 + srow) * K + k0 + skq,
                    &Bs[bi * 512]);
        }
        __syncthreads();

        short8 af[4], bf[4];
#pragma unroll
        for (int m = 0; m < 4; ++m)
            af[m] = *reinterpret_cast<const short8*>(
                &As[(wr * 64 + m * 16 + laneRow) * GBK + laneK]);
#pragma unroll
        for (int n = 0; n < 4; ++n)
            bf[n] = *reinterpret_cast<const short8*>(
                &Bs[(wc * 64 + n * 16 + laneRow) * GBK + laneK]);
#pragma unroll
        for (int m = 0; m < 4; ++m)
#pragma unroll
            for (int n = 0; n < 4; ++n)
                acc[m][n] = __builtin_amdgcn_mfma_f32_16x16x32_bf16(
                    af[m], bf[n], acc[m][n], 0, 0, 0);
        __syncthreads();
    }

    const int orow = (lane >> 4) * 4;
#pragma unroll
    for (int m = 0; m < 4; ++m) {
#pragma unroll
        for (int n = 0; n < 4; ++n) {
            int gc = col0 + wc * 64 + n * 16 + laneRow;
            if (gc >= Nn) continue;
            float bv = bias ? bias[gc] : 0.f;
#pragma unroll
            for (int j = 0; j < 4; ++j) {
                int gr = row0 + wr * 64 + m * 16 + orow + j;
                if (gr >= M) continue;
                float v = acc[m][n][j] + bv;
                if (ACT == 1) v = fmaxf(v, 0.f);
                if (OUTBF) ((ushort_t*)Cv)[(size_t)gr * Nn + gc] = f2b(v);
                else       ((float*)Cv)   [(size_t)gr * Nn + gc] = v;
            }
        }
    }
}

// ---- split-K variant: DETERMINISTIC — each z-slice plain-stores its own part
__global__ __launch_bounds__(256) void gemm_splitk_kernel(
    const ushort_t* __restrict__ A, const ushort_t* __restrict__ Bt,
    float* __restrict__ parts, int M, int Nn, int K, int KS)
{
    __shared__ ushort_t As[GBM * GBK];
    __shared__ ushort_t Bs[GBN * GBK];
    const int t = threadIdx.x;
    const int lane = t & 63;
    const int wid = t >> 6;
    const int wr = wid >> 1, wc = wid & 1;
    const int row0 = blockIdx.y * GBM, col0 = blockIdx.x * GBN;
    const int kbeg = blockIdx.z * KS, kend = kbeg + KS;
    float* C = parts + (size_t)blockIdx.z * M * Nn;
    const int laneRow = lane & 15;
    const int laneK   = (lane >> 4) * 8;
    const int srow = lane >> 2;
    const int skq  = (lane & 3) * 8;

    floatx4 acc[4][4];
#pragma unroll
    for (int m = 0; m < 4; ++m)
#pragma unroll
        for (int n = 0; n < 4; ++n)
            acc[m][n] = (floatx4){0.f, 0.f, 0.f, 0.f};

    for (int k0 = kbeg; k0 < kend; k0 += GBK) {
#pragma unroll
        for (int i = 0; i < 2; ++i) {
            int ai = wid * 2 + i;
            gload16(A + (size_t)(row0 + ai * 16 + srow) * K + k0 + skq,
                    &As[ai * 512]);
        }
#pragma unroll
        for (int i = 0; i < 2; ++i) {
            int bi = wid * 2 + i;
            gload16(Bt + (size_t)(col0 + bi * 16 + srow) * K + k0 + skq,
                    &Bs[bi * 512]);
        }
        __syncthreads();

        short8 af[4], bf[4];
#pragma unroll
        for (int m = 0; m < 4; ++m)
            af[m] = *reinterpret_cast<const short8*>(
                &As[(wr * 64 + m * 16 + laneRow) * GBK + laneK]);
#pragma unroll
        for (int n = 0; n < 4; ++n)
            bf[n] = *reinterpret_cast<const short8*>(
                &Bs[(wc * 64 + n * 16 + laneRow) * GBK + laneK]);
#pragma unroll
        for (int m = 0; m < 4; ++m)
#pragma unroll
            for (int n = 0; n < 4; ++n)
                acc[m][n] = __builtin_amdgcn_mfma_f32_16x16x32_bf16(
                    af[m], bf[n], acc[m][n], 0, 0, 0);
        __syncthreads();
    }

    const int orow = (lane >> 4) * 4;
#pragma unroll
    for (int m = 0; m < 4; ++m) {
#pragma unroll
        for (int n = 0; n < 4; ++n) {
            int gc = col0 + wc * 64 + n * 16 + laneRow;
            if (gc >= Nn) continue;
#pragma unroll
            for (int j = 0; j < 4; ++j) {
                int gr = row0 + wr * 64 + m * 16 + orow + j;
                if (gr >= M) continue;
                C[(size_t)gr * Nn + gc] = acc[m][n][j];
            }
        }
    }
}

// fixed-order part reduction: h3[i] = sum_z parts[z][i]
__global__ void reduce6_kernel(const float* __restrict__ parts,
                               float* __restrict__ h3, int n)
{
    int i = (blockIdx.x * blockDim.x + threadIdx.x) * 4;
    if (i >= n) return;
    float4 s = *reinterpret_cast<const float4*>(parts + i);
#pragma unroll
    for (int z = 1; z < 6; ++z) {
        float4 p = *reinterpret_cast<const float4*>(parts + (size_t)z * n + i);
        s.x += p.x; s.y += p.y; s.z += p.z; s.w += p.w;
    }
    *reinterpret_cast<float4*>(h3 + i) = s;
}

// ---- FC kernel: bias+ReLU fused, LDS-staged coalesced nontemporal float4 stores
__global__ __launch_bounds__(256) void gemm_fc_kernel(
    const ushort_t* __restrict__ A, const ushort_t* __restrict__ Bt,
    const float* __restrict__ bias, float* __restrict__ C,
    int M, int Nn, int K)
{
    __shared__ ushort_t As[GBM * GBK];
    __shared__ ushort_t Bs[GBN * GBK];
    __shared__ float ct[32][132];
    const int t = threadIdx.x;
    const int lane = t & 63;
    const int wid = t >> 6;
    const int wr = wid >> 1, wc = wid & 1;
    int bx = blockIdx.x, by = blockIdx.y;
    xcd_swizzle(bx, by);
    const int row0 = by * GBM, col0 = bx * GBN;
    const int laneRow = lane & 15;
    const int laneK   = (lane >> 4) * 8;
    const int srow = lane >> 2;
    const int skq  = (lane & 3) * 8;

    floatx4 acc[4][4];
#pragma unroll
    for (int m = 0; m < 4; ++m)
#pragma unroll
        for (int n = 0; n < 4; ++n)
            acc[m][n] = (floatx4){0.f, 0.f, 0.f, 0.f};

    for (int k0 = 0; k0 < K; k0 += GBK) {
#pragma unroll
        for (int i = 0; i < 2; ++i) {
            int ai = wid * 2 + i;
            gload16(A + (size_t)(row0 + ai * 16 + srow) * K + k0 + skq,
                    &As[ai * 512]);
        }
#pragma unroll
        for (int i = 0; i < 2; ++i) {
            int bi = wid * 2 + i;
            gload16(Bt + (size_t)(col0 + bi * 16 + srow) * K + k0 + skq,
                    &Bs[bi * 512]);
        }
        __syncthreads();

        short8 af[4], bf[4];
#pragma unroll
        for (int m = 0; m < 4; ++m)
            af[m] = *reinterpret_cast<const short8*>(
                &As[(wr * 64 + m * 16 + laneRow) * GBK + laneK]);
#pragma unroll
        for (int n = 0; n < 4; ++n)
            bf[n] = *reinterpret_cast<const short8*>(
                &Bs[(wc * 64 + n * 16 + laneRow) * GBK + laneK]);
#pragma unroll
        for (int m = 0; m < 4; ++m)
#pragma unroll
            for (int n = 0; n < 4; ++n)
                acc[m][n] = __builtin_amdgcn_mfma_f32_16x16x32_bf16(
                    af[m], bf[n], acc[m][n], 0, 0, 0);
        __syncthreads();
    }

    const int orow = (lane >> 4) * 4;
#pragma unroll
    for (int m = 0; m < 4; ++m) {
        __syncthreads();
#pragma unroll
        for (int n = 0; n < 4; ++n)
#pragma unroll
            for (int j = 0; j < 4; ++j)
                ct[wr * 16 + orow + j][wc * 64 + n * 16 + laneRow] = acc[m][n][j];
        __syncthreads();
#pragma unroll
        for (int i = 0; i < 4; ++i) {
            int idx = t + i * 256;
            int lr = idx >> 5, lc = (idx & 31) * 4;
            int gr = row0 + (lr & 15) + m * 16 + (lr >> 4) * 64;
            if (gr >= M) continue;
            int gc = col0 + lc;
            float4 v = *reinterpret_cast<const float4*>(&ct[lr][lc]);
            if (gc + 4 <= Nn) {
                float4 b4 = *reinterpret_cast<const float4*>(bias + gc);
                floatx4 o;
                o[0] = fmaxf(v.x + b4.x, 0.f);
                o[1] = fmaxf(v.y + b4.y, 0.f);
                o[2] = fmaxf(v.z + b4.z, 0.f);
                o[3] = fmaxf(v.w + b4.w, 0.f);
                __builtin_nontemporal_store(
                    o, reinterpret_cast<floatx4*>(C + (size_t)gr * Nn + gc));
            } else {
                float vv[4] = {v.x, v.y, v.z, v.w};
#pragma unroll
                for (int q = 0; q < 4; ++q)
                    if (gc + q < Nn)
                        C[(size_t)gr * Nn + gc + q] = fmaxf(vv[q] + bias[gc + q], 0.f);
            }
        }
    }
}

// ======================== merged prep: x convert (+pad zero) + 4 transposes ========================
__global__ __launch_bounds__(256) void prep5_kernel(
    const float* __restrict__ x, const float* __restrict__ W1,
    const float* __restrict__ W2, const float* __restrict__ W3,
    const float* __restrict__ fcW,
    ushort_t* __restrict__ xb, ushort_t* __restrict__ W1t,
    ushort_t* __restrict__ W2t, ushort_t* __restrict__ W3t,
    ushort_t* __restrict__ fcWt)
{
    int b = blockIdx.x;
    if (b < 1264) {                      // xb: MPAD*F_IN = 1264*1024; pad rows zeroed
        int i0 = b * 1024 + threadIdx.x * 4;
        ushort4 o;
        if (i0 < N_NODES * F_IN) {
            float4 v = *reinterpret_cast<const float4*>(x + i0);
            o = make_ushort4(f2b(v.x), f2b(v.y), f2b(v.z), f2b(v.w));
        } else {
            o = make_ushort4(0, 0, 0, 0);
        }
        *reinterpret_cast<ushort4*>(xb + i0) = o;
        return;
    }
    b -= 1264;
    const float* in; ushort_t* outp; int R, Cc, Kpad, tilesK;
    if (b < 240)       { in = W1;  outp = W1t;  R = 128;  Cc = 1920;  Kpad = 128;  tilesK = 4; }
    else if (b < 3840) { b -= 240;  in = W2;  outp = W2t;  R = 1920; Cc = 1920;  Kpad = 1920; tilesK = 60; }
    else if (b < 4080) { b -= 3840; in = W3;  outp = W3t;  R = 1920; Cc = 120;   Kpad = 1920; tilesK = 60; }
    else               { b -= 4080; in = fcW; outp = fcWt; R = 120;  Cc = 10000; Kpad = 128;  tilesK = 4; }
    const int k0 = (b % tilesK) * 32, n0 = (b / tilesK) * 32;
    __shared__ float tile[32][33];
    const int tx = threadIdx.x & 31, ty = threadIdx.x >> 5;
#pragma unroll
    for (int i = 0; i < 4; ++i) {
        int r = k0 + ty + i * 8, c = n0 + tx;
        tile[ty + i * 8][tx] = (r < R && c < Cc) ? in[(size_t)r * Cc + c] : 0.f;
    }
    __syncthreads();
#pragma unroll
    for (int i = 0; i < 4; ++i) {
        int orow = n0 + ty + i * 8, ocol = k0 + tx;
        outp[(size_t)orow * Kpad + ocol] = f2b(tile[tx][ty + i * 8]);
    }
}

// ======================== edge-index dtype handling ========================
__global__ void detect_kernel(const int* __restrict__ w, int nwords, int* flag)
{
    int i = blockIdx.x * blockDim.x + threadIdx.x;
    int odd = 2 * i + 1;
    if (odd < nwords && w[odd] != 0) atomicOr(flag, 1);
}

__global__ void convert_hist_kernel(const int* __restrict__ w, const int* __restrict__ flag,
                                    int* __restrict__ src, int* __restrict__ dst,
                                    int* __restrict__ deg, int E)
{
    int i = blockIdx.x * blockDim.x + threadIdx.x;
    if (i >= E) return;
    int s, d;
    if (*flag == 0) { s = w[2 * i]; d = w[2 * E + 2 * i]; }
    else            { s = w[i];     d = w[E + i]; }
    src[i] = s; dst[i] = d;
    atomicAdd(deg + d, 1);
}

// ======================== CSR build (deterministic) ========================
#define SCAN_T 1024
__global__ __launch_bounds__(SCAN_T) void scan_kernel(
    const int* __restrict__ deg, int* __restrict__ off, int n)
{
    __shared__ int part[SCAN_T];
    int t = threadIdx.x;
    int per = (n + SCAN_T - 1) / SCAN_T;
    int b0 = t * per, b1 = min(b0 + per, n);
    int s = 0;
    for (int i = b0; i < b1; ++i) s += deg[i];
    part[t] = s;
    __syncthreads();
    for (int d = 1; d < SCAN_T; d <<= 1) {
        int v = (t >= d) ? part[t - d] : 0;
        __syncthreads();
        part[t] += v;
        __syncthreads();
    }
    int run = (t == 0) ? 0 : part[t - 1];
    for (int i = b0; i < b1; ++i) { off[i] = run; run += deg[i]; }
    if (t == SCAN_T - 1) off[n] = run;
}

// provisional scatter (atomic order nondeterministic — fixed by sortseg)
__global__ void scatter_kernel(const int* __restrict__ dst, const int* __restrict__ off,
                               int* __restrict__ cnt, int* __restrict__ perm, int E)
{
    int i = blockIdx.x * blockDim.x + threadIdx.x;
    if (i >= E) return;
    int d = dst[i];
    int pos = off[d] + atomicAdd(cnt + d, 1);
    perm[pos] = i;
}

// sort each segment by original edge index (stable, deterministic), gather srcs
__global__ void sortseg_kernel(const int* __restrict__ off, int* __restrict__ perm,
                               const int* __restrict__ srcv, int* __restrict__ srcs, int Nn)
{
    int d = blockIdx.x * blockDim.x + threadIdx.x;
    if (d >= Nn) return;
    int s = off[d], e = off[d + 1];
    for (int i = s + 1; i < e; ++i) {
        int v = perm[i];
        int j = i - 1;
        while (j >= s && perm[j] > v) { perm[j + 1] = perm[j]; --j; }
        perm[j + 1] = v;
    }
    for (int i = s; i < e; ++i) srcs[i] = srcv[perm[i]];
}

// ======================== attention logits: one block per node (H=16) ========================
__global__ __launch_bounds__(256) void al_node_kernel(
    const ushort_t* __restrict__ h,
    const float* __restrict__ a_s, const float* __restrict__ a_d,
    float* __restrict__ als, float* __restrict__ ald)
{
    const int n = blockIdx.x;
    const int t = threadIdx.x;
    __shared__ float ps[240], pd[240];
    if (t < 240) {
        const int col = t * 8;
        short8 v = *reinterpret_cast<const short8*>(h + (size_t)n * 1920 + col);
        float4 s0 = *reinterpret_cast<const float4*>(a_s + col);
        float4 s1 = *reinterpret_cast<const float4*>(a_s + col + 4);
        float4 d0 = *reinterpret_cast<const float4*>(a_d + col);
        float4 d1 = *reinterpret_cast<const float4*>(a_d + col + 4);
        float f[8];
#pragma unroll
        for (int k = 0; k < 8; ++k) f[k] = b2f((ushort_t)v[k]);
        float x1 = f[0]*s0.x + f[1]*s0.y + f[2]*s0.z + f[3]*s0.w
                 + f[4]*s1.x + f[5]*s1.y + f[6]*s1.z + f[7]*s1.w;
        float x2 = f[0]*d0.x + f[1]*d0.y + f[2]*d0.z + f[3]*d0.w
                 + f[4]*d1.x + f[5]*d1.y + f[6]*d1.z + f[7]*d1.w;
        ps[t] = x1; pd[t] = x2;
    }
    __syncthreads();
    if (t < 16) {
        float s1 = 0.f, s2 = 0.f;
#pragma unroll
        for (int j = 0; j < 15; ++j) {
            s1 += ps[t * 15 + j];
            s2 += pd[t * 15 + j];
        }
        als[n * 16 + t] = s1;
        ald[n * 16 + t] = s2;
    }
}

// fp32 input variant (layer 3, H=1, Cc=120)
__global__ void al_f32_kernel(const float* __restrict__ h,
                              const float* __restrict__ a_s, const float* __restrict__ a_d,
                              float* __restrict__ als, float* __restrict__ ald, int Nn)
{
    int wid  = (blockIdx.x * blockDim.x + threadIdx.x) >> 6;
    int lane = threadIdx.x & 63;
    if (wid >= Nn) return;
    const float* hp = h + (size_t)wid * CH;
    float s1 = 0.f, s2 = 0.f;
    int c = lane * 2;
    if (c < CH) {
        float2 hv  = *reinterpret_cast<const float2*>(hp + c);
        float2 as2 = *reinterpret_cast<const float2*>(a_s + c);
        float2 ad2 = *reinterpret_cast<const float2*>(a_d + c);
        s1 = hv.x * as2.x + hv.y * as2.y;
        s2 = hv.x * ad2.x + hv.y * ad2.y;
    }
#pragma unroll
    for (int o = 32; o; o >>= 1) {
        s1 += __shfl_down(s1, o);
        s2 += __shfl_down(s2, o);
    }
    if (lane == 0) { als[wid] = s1; ald[wid] = s2; }
}

// ======================== fused online softmax + aggregation (H=16) ========================
#define SCHUNK 32
template<int ACT>
__global__ __launch_bounds__(256) void sagg_kernel(
    const ushort_t* __restrict__ h,
    const float* __restrict__ als, const float* __restrict__ ald,
    const int* __restrict__ off, const int* __restrict__ srcs,
    const float* __restrict__ bias, ushort_t* __restrict__ outb)
{
    const int d = blockIdx.x;
    const int t = threadIdx.x;
    const int start = off[d], end = off[d + 1];
    __shared__ float lAl[SCHUNK][NH];
    __shared__ int   lSrc[SCHUNK];
    __shared__ float lM[NH], lS[NH], lScale[NH], lAld[NH];
    const int col = t * 8;
    const int head = (t < 240) ? (col / CH) : 0;
    float acc[8] = {0.f, 0.f, 0.f, 0.f, 0.f, 0.f, 0.f, 0.f};
    if (t < NH) { lM[t] = -1e30f; lS[t] = 0.f; lAld[t] = ald[d * NH + t]; }
    __syncthreads();

    for (int base = start; base < end; base += SCHUNK) {
        const int nb = min(SCHUNK, end - base);
        if (t < nb) lSrc[t] = srcs[base + t];
        for (int it = t; it < nb * NH; it += 256) {
            int j = it >> 4, hh = it & 15;
            int s = srcs[base + j];
            float xx = als[s * NH + hh] + lAld[hh];
            lAl[j][hh] = (xx > 0.f) ? xx : NEG_SLOPE * xx;
        }
        __syncthreads();
        if (t < NH) {
            float mc = -1e30f;
            for (int j = 0; j < nb; ++j) mc = fmaxf(mc, lAl[j][t]);
            float mnew = fmaxf(lM[t], mc);
            float sc = __expf(lM[t] - mnew);
            float s_c = 0.f;
            for (int j = 0; j < nb; ++j) {
                float e = __expf(lAl[j][t] - mnew);
                lAl[j][t] = e;
                s_c += e;
            }
            lS[t] = lS[t] * sc + s_c;
            lM[t] = mnew;
            lScale[t] = sc;
        }
        __syncthreads();
        if (t < 240) {
            float sc = lScale[head];
#pragma unroll
            for (int k = 0; k < 8; ++k) acc[k] *= sc;
            int j = 0;
            for (; j + 4 <= nb; j += 4) {
                int s0 = lSrc[j], s1 = lSrc[j + 1], s2 = lSrc[j + 2], s3 = lSrc[j + 3];
                float a0 = lAl[j][head], a1 = lAl[j + 1][head];
                float a2 = lAl[j + 2][head], a3 = lAl[j + 3][head];
                short8 v0 = *reinterpret_cast<const short8*>(h + (size_t)s0 * 1920 + col);
                short8 v1 = *reinterpret_cast<const short8*>(h + (size_t)s1 * 1920 + col);
                short8 v2 = *reinterpret_cast<const short8*>(h + (size_t)s2 * 1920 + col);
                short8 v3 = *reinterpret_cast<const short8*>(h + (size_t)s3 * 1920 + col);
#pragma unroll
                for (int k = 0; k < 8; ++k) {
                    float p = fmaf(b2f((ushort_t)v1[k]), a1,
                                   fmaf(b2f((ushort_t)v0[k]), a0, acc[k]));
                    acc[k] = fmaf(b2f((ushort_t)v3[k]), a3,
                                  fmaf(b2f((ushort_t)v2[k]), a2, p));
                }
            }
            for (; j < nb; ++j) {
                int s0 = lSrc[j];
                float a0 = lAl[j][head];
                short8 v0 = *reinterpret_cast<const short8*>(h + (size_t)s0 * 1920 + col);
#pragma unroll
                for (int k = 0; k < 8; ++k)
                    acc[k] = fmaf(b2f((ushort_t)v0[k]), a0, acc[k]);
            }
        }
        __syncthreads();
    }

    if (t < 240) {
        float rs = 1.f / lS[head];
        short8 o;
#pragma unroll
        for (int k = 0; k < 8; ++k) {
            float v = acc[k] * rs + bias[col + k];
            if (ACT) v = (v > 0.f) ? v : expm1f(v);
            o[k] = (short)f2b(v);
        }
        *reinterpret_cast<short8*>(outb + (size_t)d * 1920 + col) = o;
    }
}

// H=1 fused variant: fp32 h [N][120], one 64-thread wave per node, bf16 out stride 128
__global__ __launch_bounds__(64) void sagg1_kernel(
    const float* __restrict__ h,
    const float* __restrict__ als, const float* __restrict__ ald,
    const int* __restrict__ off, const int* __restrict__ srcs,
    const float* __restrict__ bias, ushort_t* __restrict__ outb)
{
    const int d = blockIdx.x;
    const int t = threadIdx.x;
    const int start = off[d], end = off[d + 1];
    __shared__ float lA[64];
    __shared__ int   lSr[64];
    const float aldv = ald[d];
    float m = -1e30f, ssum = 0.f;
    float acc0 = 0.f, acc1 = 0.f;
    const int col = t * 2;

    for (int base = start; base < end; base += 64) {
        const int nb = min(64, end - base);
        float v = -1e30f;
        if (t < nb) {
            int s = srcs[base + t];
            lSr[t] = s;
            float xx = als[s] + aldv;
            v = (xx > 0.f) ? xx : NEG_SLOPE * xx;
        }
        float cm = v;
#pragma unroll
        for (int o = 32; o; o >>= 1) cm = fmaxf(cm, __shfl_xor(cm, o));
        float mnew = fmaxf(m, cm);
        float sc = __expf(m - mnew);
        float e = (t < nb) ? __expf(v - mnew) : 0.f;
        float es = e;
#pragma unroll
        for (int o = 32; o; o >>= 1) es += __shfl_xor(es, o);
        ssum = ssum * sc + es;
        m = mnew;
        lA[t] = e;
        __syncthreads();
        if (t < 60) {
            acc0 *= sc; acc1 *= sc;
            for (int j = 0; j < nb; ++j) {
                float a = lA[j];
                float2 w = *reinterpret_cast<const float2*>(h + (size_t)lSr[j] * CH + col);
                acc0 = fmaf(w.x, a, acc0);
                acc1 = fmaf(w.y, a, acc1);
            }
        }
        __syncthreads();
    }
    if (t < 60) {
        float rs = 1.f / ssum;
        float v0 = acc0 * rs + bias[col], v1 = acc1 * rs + bias[col + 1];
        unsigned o = (unsigned)f2b(v0) | ((unsigned)f2b(v1) << 16);
        *reinterpret_cast<unsigned*>(outb + (size_t)d * 128 + col) = o;
    }
}

// ======================== launch ========================
extern "C" void kernel_launch(void* const* d_in, const int* in_sizes, int n_in,
                              void* d_out, int out_size, void* d_ws, size_t ws_size,
                              hipStream_t stream)
{
    const float* x   = (const float*)d_in[0];
    const int*   ei  = (const int*)  d_in[1];
    const float* W1  = (const float*)d_in[2];
    const float* a1s = (const float*)d_in[3];
    const float* a1d = (const float*)d_in[4];
    const float* b1  = (const float*)d_in[5];
    const float* W2  = (const float*)d_in[6];
    const float* a2s = (const float*)d_in[7];
    const float* a2d = (const float*)d_in[8];
    const float* b2  = (const float*)d_in[9];
    const float* W3  = (const float*)d_in[10];
    const float* a3s = (const float*)d_in[11];
    const float* a3d = (const float*)d_in[12];
    const float* b3  = (const float*)d_in[13];
    const float* fcW = (const float*)d_in[14];
    const float* fcb = (const float*)d_in[15];

    float* out = (float*)d_out;
    const int N = N_NODES, E = N_EDGES;
    const int F16 = NH * CH;                 // 1920

    // ---- scratch inside d_out (FC overwrites all of d_out last)
    ushort_t* hraw  = (ushort_t*)out;                    // [MPAD][1920]
    ushort_t* hagg  = hraw + (size_t)MPAD * F16;         // [MPAD][1920]
    ushort_t* xb    = hagg + (size_t)MPAD * F16;         // [MPAD][128]
    ushort_t* W1t   = xb   + (size_t)MPAD * F_IN;        // [1920][128]
    ushort_t* W2t   = W1t  + (size_t)F16 * F_IN;         // [1920][1920]
    ushort_t* W3t   = W2t  + (size_t)F16 * F16;          // [128][1920]
    float*    parts = (float*)(W3t + (size_t)128 * F16); // [6][N][120] split-K parts
    float*    h3tmp = parts + (size_t)6 * N * CH;        // [N][120] fp32
    float*    als   = h3tmp + (size_t)N * CH;
    float*    ald   = als + (size_t)N * NH;
    int*      srcv  = (int*)(ald + (size_t)N * NH);
    int*      dstv  = srcv + E;
    int*      srcs  = dstv + E;
    int*      perm  = srcs + E;
    int*      flag  = perm + E;
    int*      deg   = flag + 1;                          // [N]
    int*      offv  = deg + N;                           // [N+1]
    int*      cnt   = offv + N + 1;                      // [N]
    // ---- d_ws: FC inputs (read while FC writes d_out)
    ushort_t* h3bb = (ushort_t*)d_ws;                    // [MPAD][128]
    ushort_t* fcWt = h3bb + (size_t)MPAD * 128;          // [MPAD][128]

    // ---- zeroing up front (flag..cnt contiguous -> one memset)
    hipMemsetAsync(flag, 0, (size_t)(3 * N + 2) * 4, stream);

    // ---- edge decode + deterministic CSR build
    detect_kernel      <<<(E + 255) / 256, 256, 0, stream>>>(ei, 2 * E, flag);
    convert_hist_kernel<<<(E + 255) / 256, 256, 0, stream>>>(ei, flag, srcv, dstv, deg, E);
    scan_kernel        <<<1, SCAN_T, 0, stream>>>(deg, offv, N);
    scatter_kernel     <<<(E + 255) / 256, 256, 0, stream>>>(dstv, offv, cnt, perm, E);
    sortseg_kernel     <<<(N + 255) / 256, 256, 0, stream>>>(offv, perm, srcv, srcs, N);

    // ---- merged prep (x convert + pad zero + 4 transposes)
    prep5_kernel<<<6608, 256, 0, stream>>>(x, W1, W2, W3, fcW, xb, W1t, W2t, W3t, fcWt);

    dim3 gBig(F16 / GBN, MPAD / GBM);        // (15,79)

    // =============== layer 1 ===============
    gemm_mfma_kernel<0, 1><<<gBig, 256, 0, stream>>>(xb, W1t, nullptr, hraw, N, F16, F_IN);
    al_node_kernel<<<N, 256, 0, stream>>>(hraw, a1s, a1d, als, ald);
    sagg_kernel<1><<<N, 256, 0, stream>>>(hraw, als, ald, offv, srcs, b1, hagg);

    // =============== layer 2 ===============
    gemm_mfma_kernel<0, 1><<<gBig, 256, 0, stream>>>(hagg, W2t, nullptr, hraw, N, F16, F16);
    al_node_kernel<<<N, 256, 0, stream>>>(hraw, a2s, a2d, als, ald);
    sagg_kernel<1><<<N, 256, 0, stream>>>(hraw, als, ald, offv, srcs, b2, hagg);

    // =============== layer 3 (H=1), deterministic split-K GEMM ===============
    dim3 gL3(1, MPAD / GBM, 6);              // K split 1920 -> 6 x 320
    gemm_splitk_kernel<<<gL3, 256, 0, stream>>>(hagg, W3t, parts, N, CH, F16, 320);
    reduce6_kernel<<<(N * CH / 4 + 255) / 256, 256, 0, stream>>>(parts, h3tmp, N * CH);
    al_f32_kernel<<<(N + 3) / 4, 256, 0, stream>>>(h3tmp, a3s, a3d, als, ald, N);
    sagg1_kernel<<<N, 64, 0, stream>>>(h3tmp, als, ald, offv, srcs, b3, h3bb);

    // =============== FC + ReLU (coalesced nontemporal epilogue) ===============
    dim3 gFC(MPAD / GBN, MPAD / GBM);        // (79,79); guards trim to 10000
    gemm_fc_kernel<<<gFC, 256, 0, stream>>>(h3bb, fcWt, fcb, out, N, N, 128);
}

// Round 11
// 540.854 us; speedup vs baseline: 1.2964x; 1.0128x over previous
//
#include <hip/hip_runtime.h>
#include <hip/hip_bf16.h>
#include <math.h>

#define N_NODES 10000
#define N_EDGES 100000
#define F_IN    128
#define CH      120
#define NH      16
#define NEG_SLOPE 0.2f
#define MPAD    10112          // N padded to multiple of 128

typedef unsigned short ushort_t;
typedef short short8 __attribute__((ext_vector_type(8)));
typedef float floatx4 __attribute__((ext_vector_type(4)));

__device__ inline ushort_t f2b(float f) {            // fp32->bf16 RNE
    unsigned u = __float_as_uint(f);
    unsigned r = (u + 0x7fffu + ((u >> 16) & 1u)) >> 16;
    return (ushort_t)r;
}
__device__ inline float b2f(ushort_t u) { return __uint_as_float(((unsigned)u) << 16); }

// async global->LDS, 16B per lane (dest = wave-uniform base + lane*16)
__device__ __forceinline__ void gload16(const ushort_t* g, ushort_t* l) {
    __builtin_amdgcn_global_load_lds(
        (const __attribute__((address_space(1))) unsigned int*)g,
        (__attribute__((address_space(3))) unsigned int*)l,
        16, 0, 0);
}

// bijective XCD swizzle (m204)
__device__ __forceinline__ void xcd_swizzle(int& bx, int& by) {
    int gx = gridDim.x;
    int nwg = gx * gridDim.y;
    int lin = by * gx + bx;
    int q = nwg >> 3, r = nwg & 7;
    int xcd = lin & 7, idx = lin >> 3;
    int swz = (xcd < r) ? (xcd * (q + 1) + idx)
                        : (r * (q + 1) + (xcd - r) * q + idx);
    bx = swz % gx;
    by = swz / gx;
}

// ======================== bf16 MFMA GEMM (m97 structure, BK=64 + XOR swizzle) ====
// LDS[row][chunk q] holds global k-chunk q^(row&7) (chunk = 8 shorts = 16B).
// Staged by pre-swizzling the per-lane GLOBAL source (rule #21: LDS dest linear).
#define GBM 128
#define GBN 128
#define GBK 64

#define STAGE_AB(A_, B_, k0_)                                                   \
    {                                                                           \
        _Pragma("unroll")                                                       \
        for (int i = 0; i < 4; ++i) {                                           \
            int ai = wid * 4 + i;                                               \
            gload16(A_ + (size_t)(row0 + ai * 8 + s_row) * K + (k0_) + s_kc,    \
                    &As[ai * 512]);                                             \
        }                                                                       \
        _Pragma("unroll")                                                       \
        for (int i = 0; i < 4; ++i) {                                           \
            int bi = wid * 4 + i;                                               \
            gload16(B_ + (size_t)(col0 + bi * 8 + s_row) * K + (k0_) + s_kc,    \
                    &Bs[bi * 512]);                                             \
        }                                                                       \
    }

#define MFMA_TILE()                                                             \
    {                                                                           \
        short8 af[4], bf[4];                                                    \
        _Pragma("unroll")                                                       \
        for (int kh = 0; kh < 2; ++kh) {                                        \
            const int chunk = ((c0 + kh * 4) ^ lr7) * 8;                        \
            _Pragma("unroll")                                                   \
            for (int m = 0; m < 4; ++m)                                         \
                af[m] = *reinterpret_cast<const short8*>(                       \
                    &As[(wr * 64 + m * 16 + laneRow) * GBK + chunk]);           \
            _Pragma("unroll")                                                   \
            for (int n = 0; n < 4; ++n)                                         \
                bf[n] = *reinterpret_cast<const short8*>(                       \
                    &Bs[(wc * 64 + n * 16 + laneRow) * GBK + chunk]);           \
            _Pragma("unroll")                                                   \
            for (int m = 0; m < 4; ++m)                                         \
                _Pragma("unroll")                                               \
                for (int n = 0; n < 4; ++n)                                     \
                    acc[m][n] = __builtin_amdgcn_mfma_f32_16x16x32_bf16(        \
                        af[m], bf[n], acc[m][n], 0, 0, 0);                      \
        }                                                                       \
    }

template<int ACT, int OUTBF>
__global__ __launch_bounds__(256) void gemm_mfma_kernel(
    const ushort_t* __restrict__ A, const ushort_t* __restrict__ Bt,
    const float* __restrict__ bias, void* __restrict__ Cv,
    int M, int Nn, int K)
{
    __shared__ ushort_t As[GBM * GBK];
    __shared__ ushort_t Bs[GBN * GBK];
    const int t = threadIdx.x;
    const int lane = t & 63;
    const int wid = t >> 6;
    const int wr = wid >> 1, wc = wid & 1;
    int bx = blockIdx.x, by = blockIdx.y;
    xcd_swizzle(bx, by);
    const int row0 = by * GBM, col0 = bx * GBN;
    const int laneRow = lane & 15;
    const int lr7 = laneRow & 7;
    const int c0  = lane >> 4;
    const int s_row = lane >> 3;                       // staging row 0..7
    const int s_kc  = ((lane & 7) ^ (lane >> 3)) * 8;  // pre-swizzled global chunk

    floatx4 acc[4][4];
#pragma unroll
    for (int m = 0; m < 4; ++m)
#pragma unroll
        for (int n = 0; n < 4; ++n)
            acc[m][n] = (floatx4){0.f, 0.f, 0.f, 0.f};

    for (int k0 = 0; k0 < K; k0 += GBK) {
        STAGE_AB(A, Bt, k0);
        __syncthreads();
        MFMA_TILE();
        __syncthreads();
    }

    const int orow = (lane >> 4) * 4;   // C/D: col=lane&15, row=(lane>>4)*4+j
#pragma unroll
    for (int m = 0; m < 4; ++m) {
#pragma unroll
        for (int n = 0; n < 4; ++n) {
            int gc = col0 + wc * 64 + n * 16 + laneRow;
            if (gc >= Nn) continue;
            float bv = bias ? bias[gc] : 0.f;
#pragma unroll
            for (int j = 0; j < 4; ++j) {
                int gr = row0 + wr * 64 + m * 16 + orow + j;
                if (gr >= M) continue;
                float v = acc[m][n][j] + bv;
                if (ACT == 1) v = fmaxf(v, 0.f);
                if (OUTBF) ((ushort_t*)Cv)[(size_t)gr * Nn + gc] = f2b(v);
                else       ((float*)Cv)   [(size_t)gr * Nn + gc] = v;
            }
        }
    }
}

// ---- split-K variant: DETERMINISTIC — each z-slice plain-stores its own part
__global__ __launch_bounds__(256) void gemm_splitk_kernel(
    const ushort_t* __restrict__ A, const ushort_t* __restrict__ Bt,
    float* __restrict__ parts, int M, int Nn, int K, int KS)
{
    __shared__ ushort_t As[GBM * GBK];
    __shared__ ushort_t Bs[GBN * GBK];
    const int t = threadIdx.x;
    const int lane = t & 63;
    const int wid = t >> 6;
    const int wr = wid >> 1, wc = wid & 1;
    const int row0 = blockIdx.y * GBM, col0 = blockIdx.x * GBN;
    const int kbeg = blockIdx.z * KS, kend = kbeg + KS;
    float* C = parts + (size_t)blockIdx.z * M * Nn;
    const int laneRow = lane & 15;
    const int lr7 = laneRow & 7;
    const int c0  = lane >> 4;
    const int s_row = lane >> 3;
    const int s_kc  = ((lane & 7) ^ (lane >> 3)) * 8;

    floatx4 acc[4][4];
#pragma unroll
    for (int m = 0; m < 4; ++m)
#pragma unroll
        for (int n = 0; n < 4; ++n)
            acc[m][n] = (floatx4){0.f, 0.f, 0.f, 0.f};

    for (int k0 = kbeg; k0 < kend; k0 += GBK) {
        STAGE_AB(A, Bt, k0);
        __syncthreads();
        MFMA_TILE();
        __syncthreads();
    }

    const int orow = (lane >> 4) * 4;
#pragma unroll
    for (int m = 0; m < 4; ++m) {
#pragma unroll
        for (int n = 0; n < 4; ++n) {
            int gc = col0 + wc * 64 + n * 16 + laneRow;
            if (gc >= Nn) continue;
#pragma unroll
            for (int j = 0; j < 4; ++j) {
                int gr = row0 + wr * 64 + m * 16 + orow + j;
                if (gr >= M) continue;
                C[(size_t)gr * Nn + gc] = acc[m][n][j];
            }
        }
    }
}

// ---- FC kernel: bias+ReLU fused, LDS-staged coalesced nontemporal float4 stores
__global__ __launch_bounds__(256) void gemm_fc_kernel(
    const ushort_t* __restrict__ A, const ushort_t* __restrict__ Bt,
    const float* __restrict__ bias, float* __restrict__ C,
    int M, int Nn, int K)
{
    __shared__ ushort_t As[GBM * GBK];
    __shared__ ushort_t Bs[GBN * GBK];
    __shared__ float ct[32][132];
    const int t = threadIdx.x;
    const int lane = t & 63;
    const int wid = t >> 6;
    const int wr = wid >> 1, wc = wid & 1;
    int bx = blockIdx.x, by = blockIdx.y;
    xcd_swizzle(bx, by);
    const int row0 = by * GBM, col0 = bx * GBN;
    const int laneRow = lane & 15;
    const int lr7 = laneRow & 7;
    const int c0  = lane >> 4;
    const int s_row = lane >> 3;
    const int s_kc  = ((lane & 7) ^ (lane >> 3)) * 8;

    floatx4 acc[4][4];
#pragma unroll
    for (int m = 0; m < 4; ++m)
#pragma unroll
        for (int n = 0; n < 4; ++n)
            acc[m][n] = (floatx4){0.f, 0.f, 0.f, 0.f};

    for (int k0 = 0; k0 < K; k0 += GBK) {
        STAGE_AB(A, Bt, k0);
        __syncthreads();
        MFMA_TILE();
        __syncthreads();
    }

    const int orow = (lane >> 4) * 4;
#pragma unroll
    for (int m = 0; m < 4; ++m) {
        __syncthreads();
#pragma unroll
        for (int n = 0; n < 4; ++n)
#pragma unroll
            for (int j = 0; j < 4; ++j)
                ct[wr * 16 + orow + j][wc * 64 + n * 16 + laneRow] = acc[m][n][j];
        __syncthreads();
#pragma unroll
        for (int i = 0; i < 4; ++i) {
            int idx = t + i * 256;
            int lr = idx >> 5, lc = (idx & 31) * 4;
            int gr = row0 + (lr & 15) + m * 16 + (lr >> 4) * 64;
            if (gr >= M) continue;
            int gc = col0 + lc;
            float4 v = *reinterpret_cast<const float4*>(&ct[lr][lc]);
            if (gc + 4 <= Nn) {
                float4 b4 = *reinterpret_cast<const float4*>(bias + gc);
                floatx4 o;
                o[0] = fmaxf(v.x + b4.x, 0.f);
                o[1] = fmaxf(v.y + b4.y, 0.f);
                o[2] = fmaxf(v.z + b4.z, 0.f);
                o[3] = fmaxf(v.w + b4.w, 0.f);
                __builtin_nontemporal_store(
                    o, reinterpret_cast<floatx4*>(C + (size_t)gr * Nn + gc));
            } else {
                float vv[4] = {v.x, v.y, v.z, v.w};
#pragma unroll
                for (int q = 0; q < 4; ++q)
                    if (gc + q < Nn)
                        C[(size_t)gr * Nn + gc + q] = fmaxf(vv[q] + bias[gc + q], 0.f);
            }
        }
    }
}

// ======================== merged prep: x convert (+pad zero) + 4 transposes ========================
__global__ __launch_bounds__(256) void prep5_kernel(
    const float* __restrict__ x, const float* __restrict__ W1,
    const float* __restrict__ W2, const float* __restrict__ W3,
    const float* __restrict__ fcW,
    ushort_t* __restrict__ xb, ushort_t* __restrict__ W1t,
    ushort_t* __restrict__ W2t, ushort_t* __restrict__ W3t,
    ushort_t* __restrict__ fcWt)
{
    int b = blockIdx.x;
    if (b < 1264) {                      // xb: MPAD*F_IN = 1264*1024; pad rows zeroed
        int i0 = b * 1024 + threadIdx.x * 4;
        ushort4 o;
        if (i0 < N_NODES * F_IN) {
            float4 v = *reinterpret_cast<const float4*>(x + i0);
            o = make_ushort4(f2b(v.x), f2b(v.y), f2b(v.z), f2b(v.w));
        } else {
            o = make_ushort4(0, 0, 0, 0);
        }
        *reinterpret_cast<ushort4*>(xb + i0) = o;
        return;
    }
    b -= 1264;
    const float* in; ushort_t* outp; int R, Cc, Kpad, tilesK;
    if (b < 240)       { in = W1;  outp = W1t;  R = 128;  Cc = 1920;  Kpad = 128;  tilesK = 4; }
    else if (b < 3840) { b -= 240;  in = W2;  outp = W2t;  R = 1920; Cc = 1920;  Kpad = 1920; tilesK = 60; }
    else if (b < 4080) { b -= 3840; in = W3;  outp = W3t;  R = 1920; Cc = 120;   Kpad = 1920; tilesK = 60; }
    else               { b -= 4080; in = fcW; outp = fcWt; R = 120;  Cc = 10000; Kpad = 128;  tilesK = 4; }
    const int k0 = (b % tilesK) * 32, n0 = (b / tilesK) * 32;
    __shared__ float tile[32][33];
    const int tx = threadIdx.x & 31, ty = threadIdx.x >> 5;
#pragma unroll
    for (int i = 0; i < 4; ++i) {
        int r = k0 + ty + i * 8, c = n0 + tx;
        tile[ty + i * 8][tx] = (r < R && c < Cc) ? in[(size_t)r * Cc + c] : 0.f;
    }
    __syncthreads();
#pragma unroll
    for (int i = 0; i < 4; ++i) {
        int orow = n0 + ty + i * 8, ocol = k0 + tx;
        outp[(size_t)orow * Kpad + ocol] = f2b(tile[tx][ty + i * 8]);
    }
}

// ======================== edge-index dtype handling ========================
__global__ void detect_kernel(const int* __restrict__ w, int nwords, int* flag)
{
    int i = blockIdx.x * blockDim.x + threadIdx.x;
    int odd = 2 * i + 1;
    if (odd < nwords && w[odd] != 0) atomicOr(flag, 1);
}

__global__ void convert_hist_kernel(const int* __restrict__ w, const int* __restrict__ flag,
                                    int* __restrict__ src, int* __restrict__ dst,
                                    int* __restrict__ deg, int E)
{
    int i = blockIdx.x * blockDim.x + threadIdx.x;
    if (i >= E) return;
    int s, d;
    if (*flag == 0) { s = w[2 * i]; d = w[2 * E + 2 * i]; }
    else            { s = w[i];     d = w[E + i]; }
    src[i] = s; dst[i] = d;
    atomicAdd(deg + d, 1);
}

// ======================== CSR build (deterministic) ========================
#define SCAN_T 1024
__global__ __launch_bounds__(SCAN_T) void scan_kernel(
    const int* __restrict__ deg, int* __restrict__ off, int n)
{
    __shared__ int part[SCAN_T];
    int t = threadIdx.x;
    int per = (n + SCAN_T - 1) / SCAN_T;
    int b0 = t * per, b1 = min(b0 + per, n);
    int s = 0;
    for (int i = b0; i < b1; ++i) s += deg[i];
    part[t] = s;
    __syncthreads();
    for (int d = 1; d < SCAN_T; d <<= 1) {
        int v = (t >= d) ? part[t - d] : 0;
        __syncthreads();
        part[t] += v;
        __syncthreads();
    }
    int run = (t == 0) ? 0 : part[t - 1];
    for (int i = b0; i < b1; ++i) { off[i] = run; run += deg[i]; }
    if (t == SCAN_T - 1) off[n] = run;
}

// provisional scatter (atomic order nondeterministic — fixed by sortseg)
__global__ void scatter_kernel(const int* __restrict__ dst, const int* __restrict__ off,
                               int* __restrict__ cnt, int* __restrict__ perm, int E)
{
    int i = blockIdx.x * blockDim.x + threadIdx.x;
    if (i >= E) return;
    int d = dst[i];
    int pos = off[d] + atomicAdd(cnt + d, 1);
    perm[pos] = i;
}

// sort each segment by original edge index (stable, deterministic), gather srcs
__global__ void sortseg_kernel(const int* __restrict__ off, int* __restrict__ perm,
                               const int* __restrict__ srcv, int* __restrict__ srcs, int Nn)
{
    int d = blockIdx.x * blockDim.x + threadIdx.x;
    if (d >= Nn) return;
    int s = off[d], e = off[d + 1];
    for (int i = s + 1; i < e; ++i) {
        int v = perm[i];
        int j = i - 1;
        while (j >= s && perm[j] > v) { perm[j + 1] = perm[j]; --j; }
        perm[j + 1] = v;
    }
    for (int i = s; i < e; ++i) srcs[i] = srcv[perm[i]];
}

// ======================== attention logits: 4 nodes per block (H=16) ========================
__global__ __launch_bounds__(256) void al_node_kernel(
    const ushort_t* __restrict__ h,
    const float* __restrict__ a_s, const float* __restrict__ a_d,
    float* __restrict__ als, float* __restrict__ ald)
{
    const int t = threadIdx.x;
    __shared__ float ps[240], pd[240];
#pragma unroll
    for (int it = 0; it < 4; ++it) {
        const int n = blockIdx.x * 4 + it;
        if (t < 240) {
            const int col = t * 8;
            short8 v = *reinterpret_cast<const short8*>(h + (size_t)n * 1920 + col);
            float4 s0 = *reinterpret_cast<const float4*>(a_s + col);
            float4 s1 = *reinterpret_cast<const float4*>(a_s + col + 4);
            float4 d0 = *reinterpret_cast<const float4*>(a_d + col);
            float4 d1 = *reinterpret_cast<const float4*>(a_d + col + 4);
            float f[8];
#pragma unroll
            for (int k = 0; k < 8; ++k) f[k] = b2f((ushort_t)v[k]);
            float x1 = f[0]*s0.x + f[1]*s0.y + f[2]*s0.z + f[3]*s0.w
                     + f[4]*s1.x + f[5]*s1.y + f[6]*s1.z + f[7]*s1.w;
            float x2 = f[0]*d0.x + f[1]*d0.y + f[2]*d0.z + f[3]*d0.w
                     + f[4]*d1.x + f[5]*d1.y + f[6]*d1.z + f[7]*d1.w;
            ps[t] = x1; pd[t] = x2;
        }
        __syncthreads();
        if (t < 16) {
            float s1 = 0.f, s2 = 0.f;
#pragma unroll
            for (int j = 0; j < 15; ++j) {
                s1 += ps[t * 15 + j];
                s2 += pd[t * 15 + j];
            }
            als[n * 16 + t] = s1;
            ald[n * 16 + t] = s2;
        }
        __syncthreads();
    }
}

// ======================== fused split-K reduce + layer-3 logits ========================
// One wave per node: h3 = sum_z parts[z] (fixed order), als/ald = dot(h3, a3s/a3d)
__global__ void reduce_al_kernel(const float* __restrict__ parts,
                                 float* __restrict__ h3,
                                 const float* __restrict__ a_s, const float* __restrict__ a_d,
                                 float* __restrict__ als, float* __restrict__ ald, int Nn)
{
    int wid  = (blockIdx.x * blockDim.x + threadIdx.x) >> 6;
    int lane = threadIdx.x & 63;
    if (wid >= Nn) return;
    int c = lane * 2;
    float d1 = 0.f, d2 = 0.f;
    if (c < CH) {
        size_t base = (size_t)wid * CH + c;
        float sx = 0.f, sy = 0.f;
#pragma unroll
        for (int z = 0; z < 6; ++z) {
            float2 p = *reinterpret_cast<const float2*>(parts + (size_t)z * Nn * CH + base);
            sx += p.x; sy += p.y;
        }
        *reinterpret_cast<float2*>(h3 + base) = make_float2(sx, sy);
        float2 as2 = *reinterpret_cast<const float2*>(a_s + c);
        float2 ad2 = *reinterpret_cast<const float2*>(a_d + c);
        d1 = sx * as2.x + sy * as2.y;
        d2 = sx * ad2.x + sy * ad2.y;
    }
#pragma unroll
    for (int o = 32; o; o >>= 1) {
        d1 += __shfl_down(d1, o);
        d2 += __shfl_down(d2, o);
    }
    if (lane == 0) { als[wid] = d1; ald[wid] = d2; }
}

// ======================== fused online softmax + aggregation (H=16) ========================
#define SCHUNK 32
template<int ACT>
__global__ __launch_bounds__(256) void sagg_kernel(
    const ushort_t* __restrict__ h,
    const float* __restrict__ als, const float* __restrict__ ald,
    const int* __restrict__ off, const int* __restrict__ srcs,
    const float* __restrict__ bias, ushort_t* __restrict__ outb)
{
    const int d = blockIdx.x;
    const int t = threadIdx.x;
    const int start = off[d], end = off[d + 1];
    __shared__ float lAl[SCHUNK][NH];
    __shared__ int   lSrc[SCHUNK];
    __shared__ float lM[NH], lS[NH], lScale[NH], lAld[NH];
    const int col = t * 8;
    const int head = (t < 240) ? (col / CH) : 0;
    float acc[8] = {0.f, 0.f, 0.f, 0.f, 0.f, 0.f, 0.f, 0.f};
    if (t < NH) { lM[t] = -1e30f; lS[t] = 0.f; lAld[t] = ald[d * NH + t]; }
    __syncthreads();

    for (int base = start; base < end; base += SCHUNK) {
        const int nb = min(SCHUNK, end - base);
        if (t < nb) lSrc[t] = srcs[base + t];
        for (int it = t; it < nb * NH; it += 256) {
            int j = it >> 4, hh = it & 15;
            int s = srcs[base + j];
            float xx = als[s * NH + hh] + lAld[hh];
            lAl[j][hh] = (xx > 0.f) ? xx : NEG_SLOPE * xx;
        }
        __syncthreads();
        if (t < NH) {
            float mc = -1e30f;
            for (int j = 0; j < nb; ++j) mc = fmaxf(mc, lAl[j][t]);
            float mnew = fmaxf(lM[t], mc);
            float sc = __expf(lM[t] - mnew);
            float s_c = 0.f;
            for (int j = 0; j < nb; ++j) {
                float e = __expf(lAl[j][t] - mnew);
                lAl[j][t] = e;
                s_c += e;
            }
            lS[t] = lS[t] * sc + s_c;
            lM[t] = mnew;
            lScale[t] = sc;
        }
        __syncthreads();
        if (t < 240) {
            float sc = lScale[head];
#pragma unroll
            for (int k = 0; k < 8; ++k) acc[k] *= sc;
            int j = 0;
            for (; j + 4 <= nb; j += 4) {
                int s0 = lSrc[j], s1 = lSrc[j + 1], s2 = lSrc[j + 2], s3 = lSrc[j + 3];
                float a0 = lAl[j][head], a1 = lAl[j + 1][head];
                float a2 = lAl[j + 2][head], a3 = lAl[j + 3][head];
                short8 v0 = *reinterpret_cast<const short8*>(h + (size_t)s0 * 1920 + col);
                short8 v1 = *reinterpret_cast<const short8*>(h + (size_t)s1 * 1920 + col);
                short8 v2 = *reinterpret_cast<const short8*>(h + (size_t)s2 * 1920 + col);
                short8 v3 = *reinterpret_cast<const short8*>(h + (size_t)s3 * 1920 + col);
#pragma unroll
                for (int k = 0; k < 8; ++k) {
                    float p = fmaf(b2f((ushort_t)v1[k]), a1,
                                   fmaf(b2f((ushort_t)v0[k]), a0, acc[k]));
                    acc[k] = fmaf(b2f((ushort_t)v3[k]), a3,
                                  fmaf(b2f((ushort_t)v2[k]), a2, p));
                }
            }
            for (; j < nb; ++j) {
                int s0 = lSrc[j];
                float a0 = lAl[j][head];
                short8 v0 = *reinterpret_cast<const short8*>(h + (size_t)s0 * 1920 + col);
#pragma unroll
                for (int k = 0; k < 8; ++k)
                    acc[k] = fmaf(b2f((ushort_t)v0[k]), a0, acc[k]);
            }
        }
        __syncthreads();
    }

    if (t < 240) {
        float rs = 1.f / lS[head];
        short8 o;
#pragma unroll
        for (int k = 0; k < 8; ++k) {
            float v = acc[k] * rs + bias[col + k];
            if (ACT) v = (v > 0.f) ? v : expm1f(v);
            o[k] = (short)f2b(v);
        }
        *reinterpret_cast<short8*>(outb + (size_t)d * 1920 + col) = o;
    }
}

// H=1 fused variant: fp32 h [N][120], one 64-thread wave per node, bf16 out stride 128
__global__ __launch_bounds__(64) void sagg1_kernel(
    const float* __restrict__ h,
    const float* __restrict__ als, const float* __restrict__ ald,
    const int* __restrict__ off, const int* __restrict__ srcs,
    const float* __restrict__ bias, ushort_t* __restrict__ outb)
{
    const int d = blockIdx.x;
    const int t = threadIdx.x;
    const int start = off[d], end = off[d + 1];
    __shared__ float lA[64];
    __shared__ int   lSr[64];
    const float aldv = ald[d];
    float m = -1e30f, ssum = 0.f;
    float acc0 = 0.f, acc1 = 0.f;
    const int col = t * 2;

    for (int base = start; base < end; base += 64) {
        const int nb = min(64, end - base);
        float v = -1e30f;
        if (t < nb) {
            int s = srcs[base + t];
            lSr[t] = s;
            float xx = als[s] + aldv;
            v = (xx > 0.f) ? xx : NEG_SLOPE * xx;
        }
        float cm = v;
#pragma unroll
        for (int o = 32; o; o >>= 1) cm = fmaxf(cm, __shfl_xor(cm, o));
        float mnew = fmaxf(m, cm);
        float sc = __expf(m - mnew);
        float e = (t < nb) ? __expf(v - mnew) : 0.f;
        float es = e;
#pragma unroll
        for (int o = 32; o; o >>= 1) es += __shfl_xor(es, o);
        ssum = ssum * sc + es;
        m = mnew;
        lA[t] = e;
        __syncthreads();
        if (t < 60) {
            acc0 *= sc; acc1 *= sc;
            for (int j = 0; j < nb; ++j) {
                float a = lA[j];
                float2 w = *reinterpret_cast<const float2*>(h + (size_t)lSr[j] * CH + col);
                acc0 = fmaf(w.x, a, acc0);
                acc1 = fmaf(w.y, a, acc1);
            }
        }
        __syncthreads();
    }
    if (t < 60) {
        float rs = 1.f / ssum;
        float v0 = acc0 * rs + bias[col], v1 = acc1 * rs + bias[col + 1];
        unsigned o = (unsigned)f2b(v0) | ((unsigned)f2b(v1) << 16);
        *reinterpret_cast<unsigned*>(outb + (size_t)d * 128 + col) = o;
    }
}

// ======================== launch ========================
extern "C" void kernel_launch(void* const* d_in, const int* in_sizes, int n_in,
                              void* d_out, int out_size, void* d_ws, size_t ws_size,
                              hipStream_t stream)
{
    const float* x   = (const float*)d_in[0];
    const int*   ei  = (const int*)  d_in[1];
    const float* W1  = (const float*)d_in[2];
    const float* a1s = (const float*)d_in[3];
    const float* a1d = (const float*)d_in[4];
    const float* b1  = (const float*)d_in[5];
    const float* W2  = (const float*)d_in[6];
    const float* a2s = (const float*)d_in[7];
    const float* a2d = (const float*)d_in[8];
    const float* b2  = (const float*)d_in[9];
    const float* W3  = (const float*)d_in[10];
    const float* a3s = (const float*)d_in[11];
    const float* a3d = (const float*)d_in[12];
    const float* b3  = (const float*)d_in[13];
    const float* fcW = (const float*)d_in[14];
    const float* fcb = (const float*)d_in[15];

    float* out = (float*)d_out;
    const int N = N_NODES, E = N_EDGES;
    const int F16 = NH * CH;                 // 1920

    // ---- scratch inside d_out (FC overwrites all of d_out last)
    ushort_t* hraw  = (ushort_t*)out;                    // [MPAD][1920]
    ushort_t* hagg  = hraw + (size_t)MPAD * F16;         // [MPAD][1920]
    ushort_t* xb    = hagg + (size_t)MPAD * F16;         // [MPAD][128]
    ushort_t* W1t   = xb   + (size_t)MPAD * F_IN;        // [1920][128]
    ushort_t* W2t   = W1t  + (size_t)F16 * F_IN;         // [1920][1920]
    ushort_t* W3t   = W2t  + (size_t)F16 * F16;          // [128][1920]
    float*    parts = (float*)(W3t + (size_t)128 * F16); // [6][N][120] split-K parts
    float*    h3tmp = parts + (size_t)6 * N * CH;        // [N][120] fp32
    float*    als   = h3tmp + (size_t)N * CH;
    float*    ald   = als + (size_t)N * NH;
    int*      srcv  = (int*)(ald + (size_t)N * NH);
    int*      dstv  = srcv + E;
    int*      srcs  = dstv + E;
    int*      perm  = srcs + E;
    int*      flag  = perm + E;
    int*      deg   = flag + 1;                          // [N]
    int*      offv  = deg + N;                           // [N+1]
    int*      cnt   = offv + N + 1;                      // [N]
    // ---- d_ws: FC inputs (read while FC writes d_out)
    ushort_t* h3bb = (ushort_t*)d_ws;                    // [MPAD][128]
    ushort_t* fcWt = h3bb + (size_t)MPAD * 128;          // [MPAD][128]

    // ---- zeroing up front (flag..cnt contiguous -> one memset)
    hipMemsetAsync(flag, 0, (size_t)(3 * N + 2) * 4, stream);

    // ---- edge decode + deterministic CSR build
    detect_kernel      <<<(E + 255) / 256, 256, 0, stream>>>(ei, 2 * E, flag);
    convert_hist_kernel<<<(E + 255) / 256, 256, 0, stream>>>(ei, flag, srcv, dstv, deg, E);
    scan_kernel        <<<1, SCAN_T, 0, stream>>>(deg, offv, N);
    scatter_kernel     <<<(E + 255) / 256, 256, 0, stream>>>(dstv, offv, cnt, perm, E);
    sortseg_kernel     <<<(N + 255) / 256, 256, 0, stream>>>(offv, perm, srcv, srcs, N);

    // ---- merged prep (x convert + pad zero + 4 transposes)
    prep5_kernel<<<6608, 256, 0, stream>>>(x, W1, W2, W3, fcW, xb, W1t, W2t, W3t, fcWt);

    dim3 gBig(F16 / GBN, MPAD / GBM);        // (15,79)

    // =============== layer 1 ===============
    gemm_mfma_kernel<0, 1><<<gBig, 256, 0, stream>>>(xb, W1t, nullptr, hraw, N, F16, F_IN);
    al_node_kernel<<<N / 4, 256, 0, stream>>>(hraw, a1s, a1d, als, ald);
    sagg_kernel<1><<<N, 256, 0, stream>>>(hraw, als, ald, offv, srcs, b1, hagg);

    // =============== layer 2 ===============
    gemm_mfma_kernel<0, 1><<<gBig, 256, 0, stream>>>(hagg, W2t, nullptr, hraw, N, F16, F16);
    al_node_kernel<<<N / 4, 256, 0, stream>>>(hraw, a2s, a2d, als, ald);
    sagg_kernel<1><<<N, 256, 0, stream>>>(hraw, als, ald, offv, srcs, b2, hagg);

    // =============== layer 3 (H=1), deterministic split-K GEMM ===============
    dim3 gL3(1, MPAD / GBM, 6);              // K split 1920 -> 6 x 320
    gemm_splitk_kernel<<<gL3, 256, 0, stream>>>(hagg, W3t, parts, N, CH, F16, 320);
    reduce_al_kernel<<<(N + 3) / 4, 256, 0, stream>>>(parts, h3tmp, a3s, a3d, als, ald, N);
    sagg1_kernel<<<N, 64, 0, stream>>>(h3tmp, als, ald, offv, srcs, b3, h3bb);

    // =============== FC + ReLU (coalesced nontemporal epilogue) ===============
    dim3 gFC(MPAD / GBN, MPAD / GBM);        // (79,79); guards trim to 10000
    gemm_fc_kernel<<<gFC, 256, 0, stream>>>(h3bb, fcWt, fcb, out, N, N, 128);
}